// Round 11
// baseline (1518.921 us; speedup 1.0000x reference)
//
#include <hip/hip_runtime.h>

#define D 64
#define R 4
#define H_ATT 32
#define SSH 11              // dst-range size shift: S = 2048 nodes
#define SRANGE 2048
#define MAXRANGE 64         // max ranges/relation (N <= 131072)
#define PACK_SH 19          // staged word = (d_local << 19) | src  (N < 524288)
#define QSCALE 4096.0f

typedef __bf16 bf16x4 __attribute__((ext_vector_type(4)));
typedef __bf16 bf16x8 __attribute__((ext_vector_type(8)));
typedef float f32x4 __attribute__((ext_vector_type(4)));
typedef short short4_t __attribute__((ext_vector_type(4)));
typedef short short8_t __attribute__((ext_vector_type(8)));

// ============ CSR build: single-pass radix partition, per-bucket fill ============

__global__ __launch_bounds__(256) void k_bcount(const int* __restrict__ dst,
                                                int* __restrict__ bcount,
                                                int E, int nrange) {
    __shared__ int cnt[4][MAXRANGE];
    int r = blockIdx.y;
    const int* dstr = dst + (size_t)r * E;
    int wid = threadIdx.x >> 6;
    for (int i = threadIdx.x; i < 4 * MAXRANGE; i += 256) cnt[i >> 6][i & 63] = 0;
    __syncthreads();
    int stride = gridDim.x * 256;
    for (int e = blockIdx.x * 256 + threadIdx.x; e < E; e += stride)
        atomicAdd(&cnt[wid][__builtin_nontemporal_load(&dstr[e]) >> SSH], 1);
    __syncthreads();
    for (int i = threadIdx.x; i < nrange; i += 256) {
        int tot = cnt[0][i] + cnt[1][i] + cnt[2][i] + cnt[3][i];
        if (tot) atomicAdd(&bcount[r * nrange + i], tot);
    }
}

__global__ void k_bscan(const int* __restrict__ bcount, int* __restrict__ bstart,
                        int* __restrict__ gcur, int nbuck) {
    __shared__ int tmp[257];
    int t = threadIdx.x;
    if (t < nbuck) tmp[t] = bcount[t];
    __syncthreads();
    if (t == 0) {
        int run = 0;
        for (int i = 0; i < nbuck; i++) { int v = tmp[i]; tmp[i] = run; run += v; }
        tmp[nbuck] = run;
    }
    __syncthreads();
    if (t <= nbuck) bstart[t] = tmp[t];
    if (t < nbuck) gcur[t] = tmp[t];
}

__global__ __launch_bounds__(512) void k_part(const int* __restrict__ src,
                                              const int* __restrict__ dst,
                                              int* __restrict__ gcur,
                                              int* __restrict__ staged,
                                              int E, int nrange) {
    __shared__ int cnt[MAXRANGE];
    __shared__ int gbase[MAXRANGE];
    int r = blockIdx.y;
    const int* dstr = dst + (size_t)r * E;
    const int* srcr = src + (size_t)r * E;
    int* gcr = gcur + r * nrange;
    int t = threadIdx.x;
    int nsb = (E + 4095) >> 12;
    for (int sb = blockIdx.x; sb < nsb; sb += gridDim.x) {
        int e0 = sb << 12;
        for (int i = t; i < nrange; i += 512) cnt[i] = 0;
        __syncthreads();
        int pk[8], rk[8], lb[8];
        bool val[8];
        for (int u = 0; u < 8; u++) {
            int e = e0 + u * 512 + t;
            val[u] = e < E;
            if (val[u]) {
                int d = __builtin_nontemporal_load(&dstr[e]);
                int s = __builtin_nontemporal_load(&srcr[e]);
                lb[u] = d >> SSH;
                pk[u] = ((d & (SRANGE - 1)) << PACK_SH) | s;
                rk[u] = atomicAdd(&cnt[lb[u]], 1);
            }
        }
        __syncthreads();
        for (int i = t; i < nrange; i += 512) {
            int c = cnt[i];
            gbase[i] = c ? atomicAdd(&gcr[i], c) : 0;
        }
        __syncthreads();
        for (int u = 0; u < 8; u++) {
            if (val[u])
                __builtin_nontemporal_store(pk[u], &staged[gbase[lb[u]] + rk[u]]);
        }
        __syncthreads();
    }
}

// Fused per-bucket: LDS degree hist -> block scan -> offs/degi -> cursor fill.
__global__ __launch_bounds__(1024) void k_csr2(const int* __restrict__ staged,
                                               const int* __restrict__ bstart,
                                               int* __restrict__ offs,
                                               int* __restrict__ degi,
                                               int* __restrict__ esrc,
                                               int N, int nrange) {
    __shared__ int hist[SRANGE];
    __shared__ int wp[16];
    int b = blockIdx.x;
    int r = b / nrange, range = b - r * nrange;
    int base = range << SSH;
    int slen = min(SRANGE, N - base);
    int t = threadIdx.x;
    for (int i = t; i < SRANGE; i += 1024) hist[i] = 0;
    __syncthreads();
    int p0 = bstart[b], p1 = bstart[b + 1];
    for (int p = p0 + t; p < p1; p += 1024)
        atomicAdd(&hist[(unsigned)staged[p] >> PACK_SH], 1);
    __syncthreads();
    int a0 = hist[2 * t], a1 = hist[2 * t + 1];
    int s = a0 + a1;
    int lane = t & 63, wid = t >> 6;
    int x = s;
    for (int o = 1; o < 64; o <<= 1) {
        int y = __shfl_up(x, o);
        if (lane >= o) x += y;
    }
    if (lane == 63) wp[wid] = x;
    __syncthreads();
    if (t == 0) {
        int run = 0;
        for (int i = 0; i < 16; i++) { int v = wp[i]; wp[i] = run; run += v; }
    }
    __syncthreads();
    int ex = wp[wid] + (x - s);
    hist[2 * t] = ex;
    hist[2 * t + 1] = ex + a0;
    if (2 * t < slen) {
        offs[r * N + base + 2 * t] = p0 + ex;
        degi[r * N + base + 2 * t] = a0;
    }
    if (2 * t + 1 < slen) {
        offs[r * N + base + 2 * t + 1] = p0 + ex + a0;
        degi[r * N + base + 2 * t + 1] = a1;
    }
    __syncthreads();
    for (int p = p0 + t; p < p1; p += 1024) {
        int w = staged[p];
        int dloc = (unsigned)w >> PACK_SH;
        int pos = p0 + atomicAdd(&hist[dloc], 1);
        esrc[pos] = w & ((1 << PACK_SH) - 1);
    }
}

// ============ weight precompute: transposed bf16 hi/lo (once per call) ============
__global__ void k_prep(const float* __restrict__ W1, const float* __restrict__ W2,
                       const float* __restrict__ a1W, const float* __restrict__ a2W,
                       __bf16* __restrict__ WtHi, __bf16* __restrict__ WtLo,
                       __bf16* __restrict__ attWtHi) {
    int idx = blockIdx.x * 256 + threadIdx.x;
    if (idx < 32768) {
        int layer = idx >> 14;
        int rem = idx & 16383;
        int r = rem >> 12;
        int ce = rem & 4095;
        int c = ce >> 6, k = ce & 63;
        const float* W = layer ? W2 : W1;
        float w = W[r * 4096 + k * 64 + c];
        __bf16 hi = (__bf16)w;
        __bf16 lo = (__bf16)(w - (float)hi);
        WtHi[idx] = hi;
        WtLo[idx] = lo;
    } else if (idx < 32768 + 4096) {
        int i2 = idx - 32768;
        int layer = i2 >> 11;
        int rem = i2 & 2047;
        int m = rem >> 6, k = rem & 63;
        const float* aW = layer ? a2W : a1W;
        attWtHi[i2] = (__bf16)(aW[k * H_ATT + m]);
    }
}

// ============ int16 quantization, quarter-blocked xq [4][N][16] ============
__global__ void k_quant(const float* __restrict__ xin, short* __restrict__ xq,
                        int total4, int N) {
    int idx = blockIdx.x * 256 + threadIdx.x;
    if (idx >= total4) return;
    int n = idx >> 4, sub = idx & 15;
    int q = sub >> 2, wi = sub & 3;
    float4 v = reinterpret_cast<const float4*>(xin)[idx];
    short4_t qv;
    int a;
    a = (int)rintf(v.x * QSCALE); a = min(max(a, -32767), 32767); qv[0] = (short)a;
    a = (int)rintf(v.y * QSCALE); a = min(max(a, -32767), 32767); qv[1] = (short)a;
    a = (int)rintf(v.z * QSCALE); a = min(max(a, -32767), 32767); qv[2] = (short)a;
    a = (int)rintf(v.w * QSCALE); a = min(max(a, -32767), 32767); qv[3] = (short)a;
    *reinterpret_cast<short4_t*>(&xq[(size_t)q * N * 16 + (size_t)n * 16 + wi * 4]) = qv;
}

// ============ per-layer kernels ============

// gather v5: grid (N, 4 quarters), x-major dispatch -> resident cohort works one
// 3.2MB xq quarter at a time (fits each XCD L2). Wave w = relation w.
// Lane l: edge subgroup eg = l>>3 (8 edges/VMEM instr), feature pair fp = l&7.
// Register int32 accumulation; 3 shfl_xor to reduce across edge subgroups.
__global__ __launch_bounds__(256) void k_gather(const short* __restrict__ xq,
                                                const int* __restrict__ esrc,
                                                const int* __restrict__ offs,
                                                const int* __restrict__ degi,
                                                short* __restrict__ aggq, int N) {
    int n = blockIdx.x;
    int q = blockIdx.y;
    int w = threadIdx.x >> 6;
    int l = threadIdx.x & 63;
    int fp = l & 7;
    int eg = l >> 3;
    int idx = w * N + n;
    int eo = offs[idx];
    int cnt = degi[idx];
    const char* xb = (const char*)(xq + (size_t)q * N * 16);
    int a0 = 0, a1 = 0;
    for (int b0 = 0; b0 < cnt; b0 += 64) {
        int lim = cnt - b0;
        lim = lim < 64 ? lim : 64;
        int sv = (l < lim) ? __builtin_nontemporal_load(&esrc[eo + b0 + l]) : 0;
        #pragma unroll 2
        for (int j = 0; j < lim; j += 8) {
            int s = __shfl(sv, j + eg);
            bool act = (j + eg) < lim;
            int v = act ? *(const int*)(xb + (unsigned)s * 32u + (unsigned)fp * 4u) : 0;
            a0 += (int)(short)(v & 0xffff);
            a1 += (v >> 16);
        }
    }
    a0 += __shfl_xor(a0, 8);  a1 += __shfl_xor(a1, 8);
    a0 += __shfl_xor(a0, 16); a1 += __shfl_xor(a1, 16);
    a0 += __shfl_xor(a0, 32); a1 += __shfl_xor(a1, 32);
    if (l < 8) {
        float inv = 1.f / fmaxf((float)cnt, 1.f);
        int p0 = (int)rintf((float)a0 * inv);
        int p1 = (int)rintf((float)a1 * inv);
        int packed = (p0 & 0xffff) | (p1 << 16);
        *(int*)(&aggq[(size_t)q * N * R * 16 + ((size_t)n * R + w) * 16 + fp * 2]) = packed;
    }
}

// Fused: h = relu(agg @ W[r] + b[r]) via split-bf16 MFMA; score via bf16 MFMA.
// agg/h int16 in QSCALE units, quarter-major [4][N*R][16]; in-place.
#define OFF_A_HI 0
#define OFF_A_LO 8192
#define OFF_B_HI 16384
#define OFF_B_LO 24576
#define OFF_ATTW 32768
__global__ __launch_bounds__(256) void k_rgemm(
        short* hbuf, const __bf16* __restrict__ WtHi, const __bf16* __restrict__ WtLo,
        const __bf16* __restrict__ attWHi, const float* __restrict__ bias,
        const float* __restrict__ attb, const float* __restrict__ attv,
        float* __restrict__ wspread, int N) {
    __shared__ __align__(16) char L[36864];
    float* hs = (float*)L;
    int t = threadIdx.x;
    int r = blockIdx.y;
    int n0 = blockIdx.x * 64;
    const float IQ = 1.f / QSCALE;
    size_t QS = (size_t)N * R * 16;

    for (int rep = 0; rep < 4; rep++) {
        int row = rep * 16 + (t >> 4);
        int kq = t & 15;
        int q = kq >> 2, wi = kq & 3;
        short4_t qv = {0, 0, 0, 0};
        if (n0 + row < N)
            qv = *reinterpret_cast<const short4_t*>(
                &hbuf[q * QS + ((size_t)(n0 + row) * R + r) * 16 + wi * 4]);
        bf16x4 hv, lv;
        for (int j = 0; j < 4; j++) {
            float f = (float)qv[j] * IQ;
            __bf16 h = (__bf16)f;
            hv[j] = h;
            lv[j] = (__bf16)(f - (float)h);
        }
        int boff = row * 128 + ((kq * 8) ^ ((row & 7) << 4));
        *reinterpret_cast<bf16x4*>(L + OFF_A_HI + boff) = hv;
        *reinterpret_cast<bf16x4*>(L + OFF_A_LO + boff) = lv;
    }
    {
        const char* gh = (const char*)(WtHi + (size_t)r * 4096);
        const char* gl = (const char*)(WtLo + (size_t)r * 4096);
        for (int rep = 0; rep < 2; rep++) {
            int idx = rep * 256 + t;
            int c = idx >> 3;
            int ko = (idx & 7) * 16;
            int boff = c * 128 + (ko ^ ((c & 7) << 4));
            *reinterpret_cast<uint4*>(L + OFF_B_HI + boff) =
                *reinterpret_cast<const uint4*>(gh + idx * 16);
            *reinterpret_cast<uint4*>(L + OFF_B_LO + boff) =
                *reinterpret_cast<const uint4*>(gl + idx * 16);
        }
        const char* ga = (const char*)attWHi;
        int c = t >> 3;
        int ko = (t & 7) * 16;
        int boff = c * 128 + (ko ^ ((c & 7) << 4));
        *reinterpret_cast<uint4*>(L + OFF_ATTW + boff) =
            *reinterpret_cast<const uint4*>(ga + t * 16);
    }
    __syncthreads();

    int w = t >> 6, l = t & 63;
    int lrow = l & 15, lg = l >> 4;
    int swz = (lrow & 7) << 4;

    f32x4 acc[4] = {{0.f, 0.f, 0.f, 0.f}, {0.f, 0.f, 0.f, 0.f},
                    {0.f, 0.f, 0.f, 0.f}, {0.f, 0.f, 0.f, 0.f}};
    #pragma unroll
    for (int kk = 0; kk < 2; kk++) {
        int koff = (kk * 32 + lg * 8) * 2;
        int aoff = (16 * w + lrow) * 128 + (koff ^ swz);
        bf16x8 ahi = *reinterpret_cast<const bf16x8*>(L + OFF_A_HI + aoff);
        bf16x8 alo = *reinterpret_cast<const bf16x8*>(L + OFF_A_LO + aoff);
        #pragma unroll
        for (int c = 0; c < 4; c++) {
            int boff = (16 * c + lrow) * 128 + (koff ^ swz);
            bf16x8 bhi = *reinterpret_cast<const bf16x8*>(L + OFF_B_HI + boff);
            bf16x8 blo = *reinterpret_cast<const bf16x8*>(L + OFF_B_LO + boff);
            acc[c] = __builtin_amdgcn_mfma_f32_16x16x32_bf16(ahi, bhi, acc[c], 0, 0, 0);
            acc[c] = __builtin_amdgcn_mfma_f32_16x16x32_bf16(ahi, blo, acc[c], 0, 0, 0);
            acc[c] = __builtin_amdgcn_mfma_f32_16x16x32_bf16(alo, bhi, acc[c], 0, 0, 0);
        }
    }
    __syncthreads();

    #pragma unroll
    for (int c = 0; c < 4; c++) {
        int col = 16 * c + lrow;
        float bv = bias[r * D + col];
        #pragma unroll
        for (int reg = 0; reg < 4; reg++) {
            int row = 16 * w + lg * 4 + reg;
            hs[row * 68 + col] = fmaxf(acc[c][reg] + bv, 0.f);
        }
    }
    __syncthreads();

    // store h int16, quarter-major
    for (int jj = 0; jj < 4; jj++) {
        int idx = jj * 256 + t;
        int row = idx >> 4;
        int sgq = idx & 15;
        int q = sgq >> 2, wi = sgq & 3;
        if (n0 + row < N) {
            float4 v = *reinterpret_cast<const float4*>(&hs[row * 68 + sgq * 4]);
            short4_t qv;
            float f;
            f = fminf(fmaxf(v.x * QSCALE, -32767.f), 32767.f); qv[0] = (short)(int)rintf(f);
            f = fminf(fmaxf(v.y * QSCALE, -32767.f), 32767.f); qv[1] = (short)(int)rintf(f);
            f = fminf(fmaxf(v.z * QSCALE, -32767.f), 32767.f); qv[2] = (short)(int)rintf(f);
            f = fminf(fmaxf(v.w * QSCALE, -32767.f), 32767.f); qv[3] = (short)(int)rintf(f);
            *reinterpret_cast<short4_t*>(
                &hbuf[q * QS + ((size_t)(n0 + row) * R + r) * 16 + wi * 4]) = qv;
        }
    }

    f32x4 sacc[2] = {{0.f, 0.f, 0.f, 0.f}, {0.f, 0.f, 0.f, 0.f}};
    #pragma unroll
    for (int kk = 0; kk < 2; kk++) {
        int hrow = 16 * w + lrow;
        const float* hp = hs + hrow * 68 + kk * 32 + lg * 8;
        float4 f0 = *reinterpret_cast<const float4*>(hp);
        float4 f1 = *reinterpret_cast<const float4*>(hp + 4);
        bf16x8 ha;
        ha[0] = (__bf16)f0.x; ha[1] = (__bf16)f0.y; ha[2] = (__bf16)f0.z; ha[3] = (__bf16)f0.w;
        ha[4] = (__bf16)f1.x; ha[5] = (__bf16)f1.y; ha[6] = (__bf16)f1.z; ha[7] = (__bf16)f1.w;
        int koff = (kk * 32 + lg * 8) * 2;
        #pragma unroll
        for (int c = 0; c < 2; c++) {
            int boff = (16 * c + lrow) * 128 + (koff ^ swz);
            bf16x8 bw = *reinterpret_cast<const bf16x8*>(L + OFF_ATTW + boff);
            sacc[c] = __builtin_amdgcn_mfma_f32_16x16x32_bf16(ha, bw, sacc[c], 0, 0, 0);
        }
    }
    float tot = 0.f;
    #pragma unroll
    for (int c = 0; c < 2; c++) {
        int m = 16 * c + lrow;
        float ab = attb[m], av = attv[m];
        #pragma unroll
        for (int reg = 0; reg < 4; reg++) {
            int node = n0 + 16 * w + lg * 4 + reg;
            float tv = tanhf(sacc[c][reg] + ab) * av;
            tot += (node < N) ? tv : 0.f;
        }
    }
    for (int o = 1; o < 64; o <<= 1) tot += __shfl_xor(tot, o);
    if (l == 0) atomicAdd(&wspread[r * 1024 + (blockIdx.x & 1023)], tot);
}

__global__ void k_beta(const float* __restrict__ wspread, float* __restrict__ beta, int N) {
    __shared__ float sums[4];
    int wid = threadIdx.x >> 6, lane = threadIdx.x & 63;
    float s = 0.f;
    for (int i = lane; i < 1024; i += 64) s += wspread[wid * 1024 + i];
    for (int o = 32; o > 0; o >>= 1) s += __shfl_down(s, o);
    if (lane == 0) sums[wid] = s;
    __syncthreads();
    if (threadIdx.x == 0) {
        float mean[R], m = -1e30f;
        for (int r = 0; r < R; r++) { mean[r] = sums[r] / (float)N; m = fmaxf(m, mean[r]); }
        float e[R], tot = 0.f;
        for (int r = 0; r < R; r++) { e[r] = expf(mean[r] - m); tot += e[r]; }
        for (int r = 0; r < R; r++) beta[r] = e[r] / tot;
    }
}

// combine over quarter-major int16 h: 8 threads/node (quarter x half);
// fp32 out only when dow; int16 re-quant to quartered xq when doq.
__global__ void k_combine(const short* __restrict__ hq, const float* __restrict__ beta,
                          float* __restrict__ out, short* __restrict__ xq,
                          int doq, int dow, int N) {
    int idx = blockIdx.x * blockDim.x + threadIdx.x;
    int n = idx >> 3, sub = idx & 7;
    if (n >= N) return;
    int q = sub >> 1, half = sub & 1;
    size_t QS = (size_t)N * R * 16;
    float b0 = beta[0] * (1.f / QSCALE), b1 = beta[1] * (1.f / QSCALE);
    float b2 = beta[2] * (1.f / QSCALE), b3 = beta[3] * (1.f / QSCALE);
    const short* hb = &hq[q * QS + (size_t)n * R * 16 + half * 8];
    short8_t v0 = *reinterpret_cast<const short8_t*>(hb);
    short8_t v1 = *reinterpret_cast<const short8_t*>(hb + 16);
    short8_t v2 = *reinterpret_cast<const short8_t*>(hb + 32);
    short8_t v3 = *reinterpret_cast<const short8_t*>(hb + 48);
    float o[8];
    #pragma unroll
    for (int j = 0; j < 8; j++)
        o[j] = b0 * (float)v0[j] + b1 * (float)v1[j] + b2 * (float)v2[j] + b3 * (float)v3[j];
    if (dow) {
        float4 oa = {o[0], o[1], o[2], o[3]};
        float4 ob = {o[4], o[5], o[6], o[7]};
        float4* op = reinterpret_cast<float4*>(&out[(size_t)n * D + q * 16 + half * 8]);
        op[0] = oa;
        op[1] = ob;
    }
    if (doq) {
        short8_t qv;
        #pragma unroll
        for (int j = 0; j < 8; j++) {
            float f = fminf(fmaxf(o[j] * QSCALE, -32767.f), 32767.f);
            qv[j] = (short)(int)rintf(f);
        }
        *reinterpret_cast<short8_t*>(&xq[(size_t)q * N * 16 + (size_t)n * 16 + half * 8]) = qv;
    }
}

extern "C" void kernel_launch(void* const* d_in, const int* in_sizes, int n_in,
                              void* d_out, int out_size, void* d_ws, size_t ws_size,
                              hipStream_t stream) {
    const float* x   = (const float*)d_in[0];
    const int*   src = (const int*)d_in[1];
    const int*   dst = (const int*)d_in[2];
    const float* W1  = (const float*)d_in[3];
    const float* b1  = (const float*)d_in[4];
    const float* a1W = (const float*)d_in[5];
    const float* a1b = (const float*)d_in[6];
    const float* a1v = (const float*)d_in[7];
    const float* W2  = (const float*)d_in[8];
    const float* b2  = (const float*)d_in[9];
    const float* a2W = (const float*)d_in[10];
    const float* a2b = (const float*)d_in[11];
    const float* a2v = (const float*)d_in[12];

    int N = in_sizes[0] / D;
    int E = in_sizes[1] / R;
    int RN = R * N;
    int nrange = (N + SRANGE - 1) >> SSH;   // 49 for N=100000
    int nbuck = R * nrange;                 // 196
    float* out = (float*)d_out;

    char* ws = (char*)d_ws;
    short* aggq    = (short*)ws; ws += (size_t)N * R * D * 2;   // [4][N*R][16]
    int*   degi    = (int*)ws;   ws += (size_t)RN * 4;
    int*   offs    = (int*)ws;   ws += (size_t)RN * 4;
    int*   esrc    = (int*)ws;   ws += (size_t)R * E * 4;
    int*   staged  = (int*)ws;   ws += (size_t)R * E * 4;
    short* xq      = (short*)ws; ws += (size_t)N * D * 2;       // [4][N][16]
    int*   bcount  = (int*)ws;   ws += 1024;
    int*   bstart  = (int*)ws;   ws += 1040;
    int*   gcur    = (int*)ws;   ws += 1024;
    float* wspread = (float*)ws; ws += (size_t)R * 1024 * 4;
    float* beta    = (float*)ws; ws += 64;
    __bf16* WtHi   = (__bf16*)ws; ws += 2 * R * 4096 * 2;
    __bf16* WtLo   = (__bf16*)ws; ws += 2 * R * 4096 * 2;
    __bf16* attWHi = (__bf16*)ws; ws += 2 * 2048 * 2;

    // ---- weight precompute + input quantization ----
    k_prep<<<144, 256, 0, stream>>>(W1, W2, a1W, a2W, WtHi, WtLo, attWHi);
    int total4 = N * D / 4;
    k_quant<<<(total4 + 255) / 256, 256, 0, stream>>>(x, xq, total4, N);

    // ---- CSR build ----
    hipMemsetAsync(bcount, 0, (size_t)nbuck * 4, stream);
    k_bcount<<<dim3(128, R), 256, 0, stream>>>(dst, bcount, E, nrange);
    k_bscan<<<1, 256, 0, stream>>>(bcount, bstart, gcur, nbuck);
    k_part<<<dim3(128, R), 512, 0, stream>>>(src, dst, gcur, staged, E, nrange);
    k_csr2<<<nbuck, 1024, 0, stream>>>(staged, bstart, offs, degi, esrc, N, nrange);

    int nbg = (N + 63) / 64;
    for (int layer = 0; layer < 2; layer++) {
        const float* bb = layer ? b2 : b1;
        const float* ab = layer ? a2b : a1b;
        const float* av = layer ? a2v : a1v;
        const __bf16* wh = WtHi + (size_t)layer * 16384;
        const __bf16* wl = WtLo + (size_t)layer * 16384;
        const __bf16* aw = attWHi + (size_t)layer * 2048;

        hipMemsetAsync(wspread, 0, (size_t)R * 1024 * 4, stream);
        k_gather<<<dim3(N, 4), 256, 0, stream>>>(xq, esrc, offs, degi, aggq, N);
        k_rgemm<<<dim3(nbg, R), 256, 0, stream>>>(aggq, wh, wl, aw, bb, ab, av, wspread, N);
        k_beta<<<1, 256, 0, stream>>>(wspread, beta, N);
        k_combine<<<(N * 8 + 255) / 256, 256, 0, stream>>>(
            aggq, beta, out, xq, layer == 0 ? 1 : 0, layer == 0 ? 0 : 1, N);
    }
}

// Round 12
// 777.058 us; speedup vs baseline: 1.9547x; 1.9547x over previous
//
#include <hip/hip_runtime.h>

#define D 64
#define R 4
#define H_ATT 32
#define SSH 11              // dst-range size shift: S = 2048 nodes
#define SRANGE 2048
#define MAXRANGE 64         // max ranges/relation (N <= 131072)
#define PACK_SH 19          // staged word = (d_local << 19) | src  (N < 524288)
#define QSCALE 4096.0f

typedef __bf16 bf16x4 __attribute__((ext_vector_type(4)));
typedef __bf16 bf16x8 __attribute__((ext_vector_type(8)));
typedef float f32x4 __attribute__((ext_vector_type(4)));
typedef short short4_t __attribute__((ext_vector_type(4)));
typedef short short8_t __attribute__((ext_vector_type(8)));

// ============ CSR build: single-pass radix partition, per-bucket fill ============

__global__ __launch_bounds__(256) void k_bcount(const int* __restrict__ dst,
                                                int* __restrict__ bcount,
                                                int E, int nrange) {
    __shared__ int cnt[4][MAXRANGE];
    int r = blockIdx.y;
    const int* dstr = dst + (size_t)r * E;
    int wid = threadIdx.x >> 6;
    for (int i = threadIdx.x; i < 4 * MAXRANGE; i += 256) cnt[i >> 6][i & 63] = 0;
    __syncthreads();
    int stride = gridDim.x * 256;
    for (int e = blockIdx.x * 256 + threadIdx.x; e < E; e += stride)
        atomicAdd(&cnt[wid][__builtin_nontemporal_load(&dstr[e]) >> SSH], 1);
    __syncthreads();
    for (int i = threadIdx.x; i < nrange; i += 256) {
        int tot = cnt[0][i] + cnt[1][i] + cnt[2][i] + cnt[3][i];
        if (tot) atomicAdd(&bcount[r * nrange + i], tot);
    }
}

__global__ void k_bscan(const int* __restrict__ bcount, int* __restrict__ bstart,
                        int* __restrict__ gcur, int nbuck) {
    __shared__ int tmp[257];
    int t = threadIdx.x;
    if (t < nbuck) tmp[t] = bcount[t];
    __syncthreads();
    if (t == 0) {
        int run = 0;
        for (int i = 0; i < nbuck; i++) { int v = tmp[i]; tmp[i] = run; run += v; }
        tmp[nbuck] = run;
    }
    __syncthreads();
    if (t <= nbuck) bstart[t] = tmp[t];
    if (t < nbuck) gcur[t] = tmp[t];
}

__global__ __launch_bounds__(512) void k_part(const int* __restrict__ src,
                                              const int* __restrict__ dst,
                                              int* __restrict__ gcur,
                                              int* __restrict__ staged,
                                              int E, int nrange) {
    __shared__ int cnt[MAXRANGE];
    __shared__ int gbase[MAXRANGE];
    int r = blockIdx.y;
    const int* dstr = dst + (size_t)r * E;
    const int* srcr = src + (size_t)r * E;
    int* gcr = gcur + r * nrange;
    int t = threadIdx.x;
    int nsb = (E + 4095) >> 12;
    for (int sb = blockIdx.x; sb < nsb; sb += gridDim.x) {
        int e0 = sb << 12;
        for (int i = t; i < nrange; i += 512) cnt[i] = 0;
        __syncthreads();
        int pk[8], rk[8], lb[8];
        bool val[8];
        for (int u = 0; u < 8; u++) {
            int e = e0 + u * 512 + t;
            val[u] = e < E;
            if (val[u]) {
                int d = __builtin_nontemporal_load(&dstr[e]);
                int s = __builtin_nontemporal_load(&srcr[e]);
                lb[u] = d >> SSH;
                pk[u] = ((d & (SRANGE - 1)) << PACK_SH) | s;
                rk[u] = atomicAdd(&cnt[lb[u]], 1);
            }
        }
        __syncthreads();
        for (int i = t; i < nrange; i += 512) {
            int c = cnt[i];
            gbase[i] = c ? atomicAdd(&gcr[i], c) : 0;
        }
        __syncthreads();
        for (int u = 0; u < 8; u++) {
            if (val[u])
                __builtin_nontemporal_store(pk[u], &staged[gbase[lb[u]] + rk[u]]);
        }
        __syncthreads();
    }
}

// Fused per-bucket: LDS degree hist -> block scan -> offs/degi -> cursor fill.
__global__ __launch_bounds__(1024) void k_csr2(const int* __restrict__ staged,
                                               const int* __restrict__ bstart,
                                               int* __restrict__ offs,
                                               int* __restrict__ degi,
                                               int* __restrict__ esrc,
                                               int N, int nrange) {
    __shared__ int hist[SRANGE];
    __shared__ int wp[16];
    int b = blockIdx.x;
    int r = b / nrange, range = b - r * nrange;
    int base = range << SSH;
    int slen = min(SRANGE, N - base);
    int t = threadIdx.x;
    for (int i = t; i < SRANGE; i += 1024) hist[i] = 0;
    __syncthreads();
    int p0 = bstart[b], p1 = bstart[b + 1];
    for (int p = p0 + t; p < p1; p += 1024)
        atomicAdd(&hist[(unsigned)staged[p] >> PACK_SH], 1);
    __syncthreads();
    int a0 = hist[2 * t], a1 = hist[2 * t + 1];
    int s = a0 + a1;
    int lane = t & 63, wid = t >> 6;
    int x = s;
    for (int o = 1; o < 64; o <<= 1) {
        int y = __shfl_up(x, o);
        if (lane >= o) x += y;
    }
    if (lane == 63) wp[wid] = x;
    __syncthreads();
    if (t == 0) {
        int run = 0;
        for (int i = 0; i < 16; i++) { int v = wp[i]; wp[i] = run; run += v; }
    }
    __syncthreads();
    int ex = wp[wid] + (x - s);
    hist[2 * t] = ex;
    hist[2 * t + 1] = ex + a0;
    if (2 * t < slen) {
        offs[r * N + base + 2 * t] = p0 + ex;
        degi[r * N + base + 2 * t] = a0;
    }
    if (2 * t + 1 < slen) {
        offs[r * N + base + 2 * t + 1] = p0 + ex + a0;
        degi[r * N + base + 2 * t + 1] = a1;
    }
    __syncthreads();
    for (int p = p0 + t; p < p1; p += 1024) {
        int w = staged[p];
        int dloc = (unsigned)w >> PACK_SH;
        int pos = p0 + atomicAdd(&hist[dloc], 1);
        esrc[pos] = w & ((1 << PACK_SH) - 1);
    }
}

// ============ weight precompute: transposed bf16 hi/lo (once per call) ============
__global__ void k_prep(const float* __restrict__ W1, const float* __restrict__ W2,
                       const float* __restrict__ a1W, const float* __restrict__ a2W,
                       __bf16* __restrict__ WtHi, __bf16* __restrict__ WtLo,
                       __bf16* __restrict__ attWtHi) {
    int idx = blockIdx.x * 256 + threadIdx.x;
    if (idx < 32768) {
        int layer = idx >> 14;
        int rem = idx & 16383;
        int r = rem >> 12;
        int ce = rem & 4095;
        int c = ce >> 6, k = ce & 63;
        const float* W = layer ? W2 : W1;
        float w = W[r * 4096 + k * 64 + c];
        __bf16 hi = (__bf16)w;
        __bf16 lo = (__bf16)(w - (float)hi);
        WtHi[idx] = hi;
        WtLo[idx] = lo;
    } else if (idx < 32768 + 4096) {
        int i2 = idx - 32768;
        int layer = i2 >> 11;
        int rem = i2 & 2047;
        int m = rem >> 6, k = rem & 63;
        const float* aW = layer ? a2W : a1W;
        attWtHi[i2] = (__bf16)(aW[k * H_ATT + m]);
    }
}

// ============ int16 quantization of gather operand ============
__global__ void k_quant(const float* __restrict__ xin, short* __restrict__ xq, int total4) {
    int idx = blockIdx.x * 256 + threadIdx.x;
    if (idx >= total4) return;
    float4 v = reinterpret_cast<const float4*>(xin)[idx];
    short4_t q;
    int a;
    a = (int)rintf(v.x * QSCALE); a = min(max(a, -32767), 32767); q[0] = (short)a;
    a = (int)rintf(v.y * QSCALE); a = min(max(a, -32767), 32767); q[1] = (short)a;
    a = (int)rintf(v.z * QSCALE); a = min(max(a, -32767), 32767); q[2] = (short)a;
    a = (int)rintf(v.w * QSCALE); a = min(max(a, -32767), 32767); q[3] = (short)a;
    reinterpret_cast<short4_t*>(xq)[idx] = q;
}

// ============ per-layer kernels ============

// gather (r9 structure): one block per node, wave w = relation w; int16 rows,
// 2 edges per 4B-lane load, NT esrc stream (don't evict xq rows from L2),
// exact int32 accum, int16 agg output.
__global__ __launch_bounds__(256) void k_gather(const short* __restrict__ xq,
                                                const int* __restrict__ esrc,
                                                const int* __restrict__ offs,
                                                const int* __restrict__ degi,
                                                short* __restrict__ aggq, int N) {
    int n = blockIdx.x;
    int w = threadIdx.x >> 6;
    int l = threadIdx.x & 63;
    unsigned fb = (unsigned)(l & 31) * 4u;
    int g = l >> 5;
    int idx = w * N + n;
    int eo = offs[idx];
    int cnt = degi[idx];
    const char* xb = (const char*)xq;
    int a0 = 0, a1 = 0;
    for (int b0 = 0; b0 < cnt; b0 += 64) {
        int lim = cnt - b0;
        lim = lim < 64 ? lim : 64;
        int sv = (l < lim) ? __builtin_nontemporal_load(&esrc[eo + b0 + l]) : 0;
        int j = 0;
        for (; j + 16 <= lim; j += 16) {
            int ss[8];
            #pragma unroll
            for (int u = 0; u < 8; u++) ss[u] = __shfl(sv, j + 2 * u + g);
            int vv[8];
            #pragma unroll
            for (int u = 0; u < 8; u++)
                vv[u] = *(const int*)(xb + ((unsigned)ss[u] * 128u + fb));
            #pragma unroll
            for (int u = 0; u < 8; u++) {
                a0 += (int)(short)(vv[u] & 0xffff);
                a1 += (vv[u] >> 16);
            }
        }
        for (; j + 2 <= lim; j += 2) {
            int s = __shfl(sv, j + g);
            int v = *(const int*)(xb + ((unsigned)s * 128u + fb));
            a0 += (int)(short)(v & 0xffff);
            a1 += (v >> 16);
        }
        if (j < lim) {
            int s = __shfl(sv, j);
            if (g == 0) {
                int v = *(const int*)(xb + ((unsigned)s * 128u + fb));
                a0 += (int)(short)(v & 0xffff);
                a1 += (v >> 16);
            }
        }
    }
    a0 += __shfl_xor(a0, 32);
    a1 += __shfl_xor(a1, 32);
    float inv = 1.f / fmaxf((float)cnt, 1.f);
    int q = (int)rintf((float)(g ? a1 : a0) * inv);
    aggq[((size_t)n * R + w) * D + (l & 31) * 2 + g] = (short)q;
}

// Fused: h = relu(agg @ W[r] + b[r]) via split-bf16 MFMA; score via bf16 MFMA.
// agg/h are int16 in QSCALE units; in-place (block reads its rows before writing).
#define OFF_A_HI 0
#define OFF_A_LO 8192
#define OFF_B_HI 16384
#define OFF_B_LO 24576
#define OFF_ATTW 32768
__global__ __launch_bounds__(256) void k_rgemm(
        short* hbuf, const __bf16* __restrict__ WtHi, const __bf16* __restrict__ WtLo,
        const __bf16* __restrict__ attWHi, const float* __restrict__ bias,
        const float* __restrict__ attb, const float* __restrict__ attv,
        float* __restrict__ wspread, int N) {
    __shared__ __align__(16) char L[36864];
    float* hs = (float*)L;
    int t = threadIdx.x;
    int r = blockIdx.y;
    int n0 = blockIdx.x * 64;
    const float IQ = 1.f / QSCALE;

    for (int rep = 0; rep < 4; rep++) {
        int row = rep * 16 + (t >> 4);
        int kq = (t & 15) * 4;
        short4_t qv = {0, 0, 0, 0};
        if (n0 + row < N)
            qv = *reinterpret_cast<const short4_t*>(&hbuf[((size_t)(n0 + row) * R + r) * D + kq]);
        bf16x4 hv, lv;
        for (int j = 0; j < 4; j++) {
            float f = (float)qv[j] * IQ;
            __bf16 h = (__bf16)f;
            hv[j] = h;
            lv[j] = (__bf16)(f - (float)h);
        }
        int boff = row * 128 + ((kq * 2) ^ ((row & 7) << 4));
        *reinterpret_cast<bf16x4*>(L + OFF_A_HI + boff) = hv;
        *reinterpret_cast<bf16x4*>(L + OFF_A_LO + boff) = lv;
    }
    {
        const char* gh = (const char*)(WtHi + (size_t)r * 4096);
        const char* gl = (const char*)(WtLo + (size_t)r * 4096);
        for (int rep = 0; rep < 2; rep++) {
            int idx = rep * 256 + t;
            int c = idx >> 3;
            int ko = (idx & 7) * 16;
            int boff = c * 128 + (ko ^ ((c & 7) << 4));
            *reinterpret_cast<uint4*>(L + OFF_B_HI + boff) =
                *reinterpret_cast<const uint4*>(gh + idx * 16);
            *reinterpret_cast<uint4*>(L + OFF_B_LO + boff) =
                *reinterpret_cast<const uint4*>(gl + idx * 16);
        }
        const char* ga = (const char*)attWHi;
        int c = t >> 3;
        int ko = (t & 7) * 16;
        int boff = c * 128 + (ko ^ ((c & 7) << 4));
        *reinterpret_cast<uint4*>(L + OFF_ATTW + boff) =
            *reinterpret_cast<const uint4*>(ga + t * 16);
    }
    __syncthreads();

    int w = t >> 6, l = t & 63;
    int lrow = l & 15, lg = l >> 4;
    int swz = (lrow & 7) << 4;

    f32x4 acc[4] = {{0.f, 0.f, 0.f, 0.f}, {0.f, 0.f, 0.f, 0.f},
                    {0.f, 0.f, 0.f, 0.f}, {0.f, 0.f, 0.f, 0.f}};
    #pragma unroll
    for (int kk = 0; kk < 2; kk++) {
        int koff = (kk * 32 + lg * 8) * 2;
        int aoff = (16 * w + lrow) * 128 + (koff ^ swz);
        bf16x8 ahi = *reinterpret_cast<const bf16x8*>(L + OFF_A_HI + aoff);
        bf16x8 alo = *reinterpret_cast<const bf16x8*>(L + OFF_A_LO + aoff);
        #pragma unroll
        for (int c = 0; c < 4; c++) {
            int boff = (16 * c + lrow) * 128 + (koff ^ swz);
            bf16x8 bhi = *reinterpret_cast<const bf16x8*>(L + OFF_B_HI + boff);
            bf16x8 blo = *reinterpret_cast<const bf16x8*>(L + OFF_B_LO + boff);
            acc[c] = __builtin_amdgcn_mfma_f32_16x16x32_bf16(ahi, bhi, acc[c], 0, 0, 0);
            acc[c] = __builtin_amdgcn_mfma_f32_16x16x32_bf16(ahi, blo, acc[c], 0, 0, 0);
            acc[c] = __builtin_amdgcn_mfma_f32_16x16x32_bf16(alo, bhi, acc[c], 0, 0, 0);
        }
    }
    __syncthreads();

    #pragma unroll
    for (int c = 0; c < 4; c++) {
        int col = 16 * c + lrow;
        float bv = bias[r * D + col];
        #pragma unroll
        for (int reg = 0; reg < 4; reg++) {
            int row = 16 * w + lg * 4 + reg;
            hs[row * 68 + col] = fmaxf(acc[c][reg] + bv, 0.f);
        }
    }
    __syncthreads();

    for (int jj = 0; jj < 4; jj++) {
        int idx = jj * 256 + t;
        int row = idx >> 4;
        int sg = (idx & 15) * 4;
        if (n0 + row < N) {
            float4 v = *reinterpret_cast<const float4*>(&hs[row * 68 + sg]);
            short4_t qv;
            float f;
            f = fminf(fmaxf(v.x * QSCALE, -32767.f), 32767.f); qv[0] = (short)(int)rintf(f);
            f = fminf(fmaxf(v.y * QSCALE, -32767.f), 32767.f); qv[1] = (short)(int)rintf(f);
            f = fminf(fmaxf(v.z * QSCALE, -32767.f), 32767.f); qv[2] = (short)(int)rintf(f);
            f = fminf(fmaxf(v.w * QSCALE, -32767.f), 32767.f); qv[3] = (short)(int)rintf(f);
            *reinterpret_cast<short4_t*>(&hbuf[((size_t)(n0 + row) * R + r) * D + sg]) = qv;
        }
    }

    f32x4 sacc[2] = {{0.f, 0.f, 0.f, 0.f}, {0.f, 0.f, 0.f, 0.f}};
    #pragma unroll
    for (int kk = 0; kk < 2; kk++) {
        int hrow = 16 * w + lrow;
        const float* hp = hs + hrow * 68 + kk * 32 + lg * 8;
        float4 f0 = *reinterpret_cast<const float4*>(hp);
        float4 f1 = *reinterpret_cast<const float4*>(hp + 4);
        bf16x8 ha;
        ha[0] = (__bf16)f0.x; ha[1] = (__bf16)f0.y; ha[2] = (__bf16)f0.z; ha[3] = (__bf16)f0.w;
        ha[4] = (__bf16)f1.x; ha[5] = (__bf16)f1.y; ha[6] = (__bf16)f1.z; ha[7] = (__bf16)f1.w;
        int koff = (kk * 32 + lg * 8) * 2;
        #pragma unroll
        for (int c = 0; c < 2; c++) {
            int boff = (16 * c + lrow) * 128 + (koff ^ swz);
            bf16x8 bw = *reinterpret_cast<const bf16x8*>(L + OFF_ATTW + boff);
            sacc[c] = __builtin_amdgcn_mfma_f32_16x16x32_bf16(ha, bw, sacc[c], 0, 0, 0);
        }
    }
    float tot = 0.f;
    #pragma unroll
    for (int c = 0; c < 2; c++) {
        int m = 16 * c + lrow;
        float ab = attb[m], av = attv[m];
        #pragma unroll
        for (int reg = 0; reg < 4; reg++) {
            int node = n0 + 16 * w + lg * 4 + reg;
            float tv = tanhf(sacc[c][reg] + ab) * av;
            tot += (node < N) ? tv : 0.f;
        }
    }
    for (int o = 1; o < 64; o <<= 1) tot += __shfl_xor(tot, o);
    if (l == 0) atomicAdd(&wspread[r * 1024 + (blockIdx.x & 1023)], tot);
}

// beta + self-zero of wspread for the next layer (drops one memset launch)
__global__ void k_beta(float* __restrict__ wspread, float* __restrict__ beta, int N) {
    __shared__ float sums[4];
    int wid = threadIdx.x >> 6, lane = threadIdx.x & 63;
    float s = 0.f;
    for (int i = lane; i < 1024; i += 64) s += wspread[wid * 1024 + i];
    for (int o = 32; o > 0; o >>= 1) s += __shfl_down(s, o);
    if (lane == 0) sums[wid] = s;
    __syncthreads();
    if (threadIdx.x == 0) {
        float mean[R], m = -1e30f;
        for (int r = 0; r < R; r++) { mean[r] = sums[r] / (float)N; m = fmaxf(m, mean[r]); }
        float e[R], tot = 0.f;
        for (int r = 0; r < R; r++) { e[r] = expf(mean[r] - m); tot += e[r]; }
        for (int r = 0; r < R; r++) beta[r] = e[r] / tot;
    }
    // all reads of wspread are complete (pre-barrier); zero for next layer
    for (int i = threadIdx.x; i < R * 1024; i += 256) wspread[i] = 0.f;
}

// combine over int16 h: fp32 out only when dow; int16 re-quant when doq
__global__ void k_combine(const short* __restrict__ hq, const float* __restrict__ beta,
                          float* __restrict__ out, short* __restrict__ xq,
                          int doq, int dow, int N) {
    int idx = blockIdx.x * blockDim.x + threadIdx.x;
    int n = idx >> 3, q = idx & 7;
    if (n >= N) return;
    float b0 = beta[0] * (1.f / QSCALE), b1 = beta[1] * (1.f / QSCALE);
    float b2 = beta[2] * (1.f / QSCALE), b3 = beta[3] * (1.f / QSCALE);
    const short8_t* hp = reinterpret_cast<const short8_t*>(&hq[(size_t)n * R * D]);
    short8_t v0 = hp[q], v1 = hp[8 + q], v2 = hp[16 + q], v3 = hp[24 + q];
    float o[8];
    #pragma unroll
    for (int j = 0; j < 8; j++)
        o[j] = b0 * (float)v0[j] + b1 * (float)v1[j] + b2 * (float)v2[j] + b3 * (float)v3[j];
    if (dow) {
        float4 oa = {o[0], o[1], o[2], o[3]};
        float4 ob = {o[4], o[5], o[6], o[7]};
        float4* op = reinterpret_cast<float4*>(&out[(size_t)n * D + q * 8]);
        op[0] = oa;
        op[1] = ob;
    }
    if (doq) {
        short8_t qv;
        #pragma unroll
        for (int j = 0; j < 8; j++) {
            float f = fminf(fmaxf(o[j] * QSCALE, -32767.f), 32767.f);
            qv[j] = (short)(int)rintf(f);
        }
        reinterpret_cast<short8_t*>(&xq[(size_t)n * D + q * 8])[0] = qv;
    }
}

extern "C" void kernel_launch(void* const* d_in, const int* in_sizes, int n_in,
                              void* d_out, int out_size, void* d_ws, size_t ws_size,
                              hipStream_t stream) {
    const float* x   = (const float*)d_in[0];
    const int*   src = (const int*)d_in[1];
    const int*   dst = (const int*)d_in[2];
    const float* W1  = (const float*)d_in[3];
    const float* b1  = (const float*)d_in[4];
    const float* a1W = (const float*)d_in[5];
    const float* a1b = (const float*)d_in[6];
    const float* a1v = (const float*)d_in[7];
    const float* W2  = (const float*)d_in[8];
    const float* b2  = (const float*)d_in[9];
    const float* a2W = (const float*)d_in[10];
    const float* a2b = (const float*)d_in[11];
    const float* a2v = (const float*)d_in[12];

    int N = in_sizes[0] / D;
    int E = in_sizes[1] / R;
    int RN = R * N;
    int nrange = (N + SRANGE - 1) >> SSH;   // 49 for N=100000
    int nbuck = R * nrange;                 // 196
    float* out = (float*)d_out;

    char* ws = (char*)d_ws;
    short* aggq    = (short*)ws; ws += (size_t)N * R * D * 2;   // agg/h int16, in-place
    int*   degi    = (int*)ws;   ws += (size_t)RN * 4;
    int*   offs    = (int*)ws;   ws += (size_t)RN * 4;
    int*   esrc    = (int*)ws;   ws += (size_t)R * E * 4;
    int*   staged  = (int*)ws;   ws += (size_t)R * E * 4;
    short* xq      = (short*)ws; ws += (size_t)N * D * 2;
    int*   bcount  = (int*)ws;   ws += 1024;
    int*   bstart  = (int*)ws;   ws += 1040;
    int*   gcur    = (int*)ws;   ws += 1024;
    float* wspread = (float*)ws; ws += (size_t)R * 1024 * 4;
    float* beta    = (float*)ws; ws += 64;
    __bf16* WtHi   = (__bf16*)ws; ws += 2 * R * 4096 * 2;
    __bf16* WtLo   = (__bf16*)ws; ws += 2 * R * 4096 * 2;
    __bf16* attWHi = (__bf16*)ws; ws += 2 * 2048 * 2;

    // ---- weight precompute + input quantization ----
    k_prep<<<144, 256, 0, stream>>>(W1, W2, a1W, a2W, WtHi, WtLo, attWHi);
    int total4 = N * D / 4;
    k_quant<<<(total4 + 255) / 256, 256, 0, stream>>>(x, xq, total4);

    // ---- CSR build: radix partition + fused per-bucket hist/scan/fill ----
    hipMemsetAsync(bcount, 0, (size_t)nbuck * 4, stream);
    k_bcount<<<dim3(128, R), 256, 0, stream>>>(dst, bcount, E, nrange);
    k_bscan<<<1, 256, 0, stream>>>(bcount, bstart, gcur, nbuck);
    k_part<<<dim3(128, R), 512, 0, stream>>>(src, dst, gcur, staged, E, nrange);
    k_csr2<<<nbuck, 1024, 0, stream>>>(staged, bstart, offs, degi, esrc, N, nrange);

    // wspread zero once; k_beta self-zeroes for layer 1
    hipMemsetAsync(wspread, 0, (size_t)R * 1024 * 4, stream);

    int nbg = (N + 63) / 64;
    for (int layer = 0; layer < 2; layer++) {
        const float* bb = layer ? b2 : b1;
        const float* ab = layer ? a2b : a1b;
        const float* av = layer ? a2v : a1v;
        const __bf16* wh = WtHi + (size_t)layer * 16384;
        const __bf16* wl = WtLo + (size_t)layer * 16384;
        const __bf16* aw = attWHi + (size_t)layer * 2048;

        k_gather<<<N, 256, 0, stream>>>(xq, esrc, offs, degi, aggq, N);
        k_rgemm<<<dim3(nbg, R), 256, 0, stream>>>(aggq, wh, wl, aw, bb, ab, av, wspread, N);
        k_beta<<<1, 256, 0, stream>>>(wspread, beta, N);
        // layer 0: quantize only (out write is dead); layer 1: fp32 out only
        k_combine<<<(N * 8 + 255) / 256, 256, 0, stream>>>(
            aggq, beta, out, xq, layer == 0 ? 1 : 0, layer == 0 ? 0 : 1, N);
    }
}

// Round 13
// 718.319 us; speedup vs baseline: 2.1145x; 1.0818x over previous
//
#include <hip/hip_runtime.h>

#define D 64
#define R 4
#define H_ATT 32
#define SSH 11              // dst-range size shift: S = 2048 nodes
#define SRANGE 2048
#define MAXRANGE 64         // max ranges/relation (N <= 131072)
#define PACK_SH 19          // staged word = (d_local << 19) | src  (N < 524288)
#define QSCALE 4096.0f

typedef __bf16 bf16x4 __attribute__((ext_vector_type(4)));
typedef __bf16 bf16x8 __attribute__((ext_vector_type(8)));
typedef float f32x4 __attribute__((ext_vector_type(4)));
typedef short short4_t __attribute__((ext_vector_type(4)));
typedef short short8_t __attribute__((ext_vector_type(8)));

// ============ CSR build: single-pass radix partition, per-bucket fill ============

__global__ __launch_bounds__(256) void k_bcount(const int* __restrict__ dst,
                                                int* __restrict__ bcount,
                                                int E, int nrange) {
    __shared__ int cnt[4][MAXRANGE];
    int r = blockIdx.y;
    const int* dstr = dst + (size_t)r * E;
    int wid = threadIdx.x >> 6;
    for (int i = threadIdx.x; i < 4 * MAXRANGE; i += 256) cnt[i >> 6][i & 63] = 0;
    __syncthreads();
    int stride = gridDim.x * 256;
    for (int e = blockIdx.x * 256 + threadIdx.x; e < E; e += stride)
        atomicAdd(&cnt[wid][__builtin_nontemporal_load(&dstr[e]) >> SSH], 1);
    __syncthreads();
    for (int i = threadIdx.x; i < nrange; i += 256) {
        int tot = cnt[0][i] + cnt[1][i] + cnt[2][i] + cnt[3][i];
        if (tot) atomicAdd(&bcount[r * nrange + i], tot);
    }
}

__global__ void k_bscan(const int* __restrict__ bcount, int* __restrict__ bstart,
                        int* __restrict__ gcur, int nbuck) {
    __shared__ int tmp[257];
    int t = threadIdx.x;
    if (t < nbuck) tmp[t] = bcount[t];
    __syncthreads();
    if (t == 0) {
        int run = 0;
        for (int i = 0; i < nbuck; i++) { int v = tmp[i]; tmp[i] = run; run += v; }
        tmp[nbuck] = run;
    }
    __syncthreads();
    if (t <= nbuck) bstart[t] = tmp[t];
    if (t < nbuck) gcur[t] = tmp[t];
}

__global__ __launch_bounds__(512) void k_part(const int* __restrict__ src,
                                              const int* __restrict__ dst,
                                              int* __restrict__ gcur,
                                              int* __restrict__ staged,
                                              int E, int nrange) {
    __shared__ int cnt[MAXRANGE];
    __shared__ int gbase[MAXRANGE];
    int r = blockIdx.y;
    const int* dstr = dst + (size_t)r * E;
    const int* srcr = src + (size_t)r * E;
    int* gcr = gcur + r * nrange;
    int t = threadIdx.x;
    int nsb = (E + 4095) >> 12;
    for (int sb = blockIdx.x; sb < nsb; sb += gridDim.x) {
        int e0 = sb << 12;
        for (int i = t; i < nrange; i += 512) cnt[i] = 0;
        __syncthreads();
        int pk[8], rk[8], lb[8];
        bool val[8];
        for (int u = 0; u < 8; u++) {
            int e = e0 + u * 512 + t;
            val[u] = e < E;
            if (val[u]) {
                int d = __builtin_nontemporal_load(&dstr[e]);
                int s = __builtin_nontemporal_load(&srcr[e]);
                lb[u] = d >> SSH;
                pk[u] = ((d & (SRANGE - 1)) << PACK_SH) | s;
                rk[u] = atomicAdd(&cnt[lb[u]], 1);
            }
        }
        __syncthreads();
        for (int i = t; i < nrange; i += 512) {
            int c = cnt[i];
            gbase[i] = c ? atomicAdd(&gcr[i], c) : 0;
        }
        __syncthreads();
        for (int u = 0; u < 8; u++) {
            if (val[u])
                __builtin_nontemporal_store(pk[u], &staged[gbase[lb[u]] + rk[u]]);
        }
        __syncthreads();
    }
}

// Fused per-bucket: LDS degree hist -> block scan -> offs/degi -> cursor fill.
__global__ __launch_bounds__(1024) void k_csr2(const int* __restrict__ staged,
                                               const int* __restrict__ bstart,
                                               int* __restrict__ offs,
                                               int* __restrict__ degi,
                                               int* __restrict__ esrc,
                                               int N, int nrange) {
    __shared__ int hist[SRANGE];
    __shared__ int wp[16];
    int b = blockIdx.x;
    int r = b / nrange, range = b - r * nrange;
    int base = range << SSH;
    int slen = min(SRANGE, N - base);
    int t = threadIdx.x;
    for (int i = t; i < SRANGE; i += 1024) hist[i] = 0;
    __syncthreads();
    int p0 = bstart[b], p1 = bstart[b + 1];
    for (int p = p0 + t; p < p1; p += 1024)
        atomicAdd(&hist[(unsigned)staged[p] >> PACK_SH], 1);
    __syncthreads();
    int a0 = hist[2 * t], a1 = hist[2 * t + 1];
    int s = a0 + a1;
    int lane = t & 63, wid = t >> 6;
    int x = s;
    for (int o = 1; o < 64; o <<= 1) {
        int y = __shfl_up(x, o);
        if (lane >= o) x += y;
    }
    if (lane == 63) wp[wid] = x;
    __syncthreads();
    if (t == 0) {
        int run = 0;
        for (int i = 0; i < 16; i++) { int v = wp[i]; wp[i] = run; run += v; }
    }
    __syncthreads();
    int ex = wp[wid] + (x - s);
    hist[2 * t] = ex;
    hist[2 * t + 1] = ex + a0;
    if (2 * t < slen) {
        offs[r * N + base + 2 * t] = p0 + ex;
        degi[r * N + base + 2 * t] = a0;
    }
    if (2 * t + 1 < slen) {
        offs[r * N + base + 2 * t + 1] = p0 + ex + a0;
        degi[r * N + base + 2 * t + 1] = a1;
    }
    __syncthreads();
    for (int p = p0 + t; p < p1; p += 1024) {
        int w = staged[p];
        int dloc = (unsigned)w >> PACK_SH;
        int pos = p0 + atomicAdd(&hist[dloc], 1);
        esrc[pos] = w & ((1 << PACK_SH) - 1);
    }
}

// ============ weight precompute: transposed bf16 hi/lo (once per call) ============
__global__ void k_prep(const float* __restrict__ W1, const float* __restrict__ W2,
                       const float* __restrict__ a1W, const float* __restrict__ a2W,
                       __bf16* __restrict__ WtHi, __bf16* __restrict__ WtLo,
                       __bf16* __restrict__ attWtHi) {
    int idx = blockIdx.x * 256 + threadIdx.x;
    if (idx < 32768) {
        int layer = idx >> 14;
        int rem = idx & 16383;
        int r = rem >> 12;
        int ce = rem & 4095;
        int c = ce >> 6, k = ce & 63;
        const float* W = layer ? W2 : W1;
        float w = W[r * 4096 + k * 64 + c];
        __bf16 hi = (__bf16)w;
        __bf16 lo = (__bf16)(w - (float)hi);
        WtHi[idx] = hi;
        WtLo[idx] = lo;
    } else if (idx < 32768 + 4096) {
        int i2 = idx - 32768;
        int layer = i2 >> 11;
        int rem = i2 & 2047;
        int m = rem >> 6, k = rem & 63;
        const float* aW = layer ? a2W : a1W;
        attWtHi[i2] = (__bf16)(aW[k * H_ATT + m]);
    }
}

// ============ int16 quantization of gather operand ============
__global__ void k_quant(const float* __restrict__ xin, short* __restrict__ xq, int total4) {
    int idx = blockIdx.x * 256 + threadIdx.x;
    if (idx >= total4) return;
    float4 v = reinterpret_cast<const float4*>(xin)[idx];
    short4_t q;
    int a;
    a = (int)rintf(v.x * QSCALE); a = min(max(a, -32767), 32767); q[0] = (short)a;
    a = (int)rintf(v.y * QSCALE); a = min(max(a, -32767), 32767); q[1] = (short)a;
    a = (int)rintf(v.z * QSCALE); a = min(max(a, -32767), 32767); q[2] = (short)a;
    a = (int)rintf(v.w * QSCALE); a = min(max(a, -32767), 32767); q[3] = (short)a;
    reinterpret_cast<short4_t*>(xq)[idx] = q;
}

// ============ per-layer kernels ============

// gather (r9 structure, plain loads): one block per node, wave w = relation w;
// int16 rows, 2 edges per 4B-lane load, exact int32 accum, int16 agg output.
__global__ __launch_bounds__(256) void k_gather(const short* __restrict__ xq,
                                                const int* __restrict__ esrc,
                                                const int* __restrict__ offs,
                                                const int* __restrict__ degi,
                                                short* __restrict__ aggq, int N) {
    int n = blockIdx.x;
    int w = threadIdx.x >> 6;
    int l = threadIdx.x & 63;
    unsigned fb = (unsigned)(l & 31) * 4u;
    int g = l >> 5;
    int idx = w * N + n;
    int eo = offs[idx];
    int cnt = degi[idx];
    const char* xb = (const char*)xq;
    int a0 = 0, a1 = 0;
    for (int b0 = 0; b0 < cnt; b0 += 64) {
        int lim = cnt - b0;
        lim = lim < 64 ? lim : 64;
        int sv = (l < lim) ? esrc[eo + b0 + l] : 0;
        int j = 0;
        for (; j + 16 <= lim; j += 16) {
            int ss[8];
            #pragma unroll
            for (int u = 0; u < 8; u++) ss[u] = __shfl(sv, j + 2 * u + g);
            int vv[8];
            #pragma unroll
            for (int u = 0; u < 8; u++)
                vv[u] = *(const int*)(xb + ((unsigned)ss[u] * 128u + fb));
            #pragma unroll
            for (int u = 0; u < 8; u++) {
                a0 += (int)(short)(vv[u] & 0xffff);
                a1 += (vv[u] >> 16);
            }
        }
        for (; j + 2 <= lim; j += 2) {
            int s = __shfl(sv, j + g);
            int v = *(const int*)(xb + ((unsigned)s * 128u + fb));
            a0 += (int)(short)(v & 0xffff);
            a1 += (v >> 16);
        }
        if (j < lim) {
            int s = __shfl(sv, j);
            if (g == 0) {
                int v = *(const int*)(xb + ((unsigned)s * 128u + fb));
                a0 += (int)(short)(v & 0xffff);
                a1 += (v >> 16);
            }
        }
    }
    a0 += __shfl_xor(a0, 32);
    a1 += __shfl_xor(a1, 32);
    float inv = 1.f / fmaxf((float)cnt, 1.f);
    int q = (int)rintf((float)(g ? a1 : a0) * inv);
    aggq[((size_t)n * R + w) * D + (l & 31) * 2 + g] = (short)q;
}

// Fused: h = relu(agg @ W[r] + b[r]) via split-bf16 MFMA; score via bf16 MFMA.
// agg/h are int16 in QSCALE units; in-place (block reads its rows before writing).
#define OFF_A_HI 0
#define OFF_A_LO 8192
#define OFF_B_HI 16384
#define OFF_B_LO 24576
#define OFF_ATTW 32768
__global__ __launch_bounds__(256) void k_rgemm(
        short* hbuf, const __bf16* __restrict__ WtHi, const __bf16* __restrict__ WtLo,
        const __bf16* __restrict__ attWHi, const float* __restrict__ bias,
        const float* __restrict__ attb, const float* __restrict__ attv,
        float* __restrict__ wspread, int N) {
    __shared__ __align__(16) char L[36864];
    float* hs = (float*)L;
    int t = threadIdx.x;
    int r = blockIdx.y;
    int n0 = blockIdx.x * 64;
    const float IQ = 1.f / QSCALE;

    for (int rep = 0; rep < 4; rep++) {
        int row = rep * 16 + (t >> 4);
        int kq = (t & 15) * 4;
        short4_t qv = {0, 0, 0, 0};
        if (n0 + row < N)
            qv = *reinterpret_cast<const short4_t*>(&hbuf[((size_t)(n0 + row) * R + r) * D + kq]);
        bf16x4 hv, lv;
        for (int j = 0; j < 4; j++) {
            float f = (float)qv[j] * IQ;
            __bf16 h = (__bf16)f;
            hv[j] = h;
            lv[j] = (__bf16)(f - (float)h);
        }
        int boff = row * 128 + ((kq * 2) ^ ((row & 7) << 4));
        *reinterpret_cast<bf16x4*>(L + OFF_A_HI + boff) = hv;
        *reinterpret_cast<bf16x4*>(L + OFF_A_LO + boff) = lv;
    }
    {
        const char* gh = (const char*)(WtHi + (size_t)r * 4096);
        const char* gl = (const char*)(WtLo + (size_t)r * 4096);
        for (int rep = 0; rep < 2; rep++) {
            int idx = rep * 256 + t;
            int c = idx >> 3;
            int ko = (idx & 7) * 16;
            int boff = c * 128 + (ko ^ ((c & 7) << 4));
            *reinterpret_cast<uint4*>(L + OFF_B_HI + boff) =
                *reinterpret_cast<const uint4*>(gh + idx * 16);
            *reinterpret_cast<uint4*>(L + OFF_B_LO + boff) =
                *reinterpret_cast<const uint4*>(gl + idx * 16);
        }
        const char* ga = (const char*)attWHi;
        int c = t >> 3;
        int ko = (t & 7) * 16;
        int boff = c * 128 + (ko ^ ((c & 7) << 4));
        *reinterpret_cast<uint4*>(L + OFF_ATTW + boff) =
            *reinterpret_cast<const uint4*>(ga + t * 16);
    }
    __syncthreads();

    int w = t >> 6, l = t & 63;
    int lrow = l & 15, lg = l >> 4;
    int swz = (lrow & 7) << 4;

    f32x4 acc[4] = {{0.f, 0.f, 0.f, 0.f}, {0.f, 0.f, 0.f, 0.f},
                    {0.f, 0.f, 0.f, 0.f}, {0.f, 0.f, 0.f, 0.f}};
    #pragma unroll
    for (int kk = 0; kk < 2; kk++) {
        int koff = (kk * 32 + lg * 8) * 2;
        int aoff = (16 * w + lrow) * 128 + (koff ^ swz);
        bf16x8 ahi = *reinterpret_cast<const bf16x8*>(L + OFF_A_HI + aoff);
        bf16x8 alo = *reinterpret_cast<const bf16x8*>(L + OFF_A_LO + aoff);
        #pragma unroll
        for (int c = 0; c < 4; c++) {
            int boff = (16 * c + lrow) * 128 + (koff ^ swz);
            bf16x8 bhi = *reinterpret_cast<const bf16x8*>(L + OFF_B_HI + boff);
            bf16x8 blo = *reinterpret_cast<const bf16x8*>(L + OFF_B_LO + boff);
            acc[c] = __builtin_amdgcn_mfma_f32_16x16x32_bf16(ahi, bhi, acc[c], 0, 0, 0);
            acc[c] = __builtin_amdgcn_mfma_f32_16x16x32_bf16(ahi, blo, acc[c], 0, 0, 0);
            acc[c] = __builtin_amdgcn_mfma_f32_16x16x32_bf16(alo, bhi, acc[c], 0, 0, 0);
        }
    }
    __syncthreads();

    #pragma unroll
    for (int c = 0; c < 4; c++) {
        int col = 16 * c + lrow;
        float bv = bias[r * D + col];
        #pragma unroll
        for (int reg = 0; reg < 4; reg++) {
            int row = 16 * w + lg * 4 + reg;
            hs[row * 68 + col] = fmaxf(acc[c][reg] + bv, 0.f);
        }
    }
    __syncthreads();

    for (int jj = 0; jj < 4; jj++) {
        int idx = jj * 256 + t;
        int row = idx >> 4;
        int sg = (idx & 15) * 4;
        if (n0 + row < N) {
            float4 v = *reinterpret_cast<const float4*>(&hs[row * 68 + sg]);
            short4_t qv;
            float f;
            f = fminf(fmaxf(v.x * QSCALE, -32767.f), 32767.f); qv[0] = (short)(int)rintf(f);
            f = fminf(fmaxf(v.y * QSCALE, -32767.f), 32767.f); qv[1] = (short)(int)rintf(f);
            f = fminf(fmaxf(v.z * QSCALE, -32767.f), 32767.f); qv[2] = (short)(int)rintf(f);
            f = fminf(fmaxf(v.w * QSCALE, -32767.f), 32767.f); qv[3] = (short)(int)rintf(f);
            *reinterpret_cast<short4_t*>(&hbuf[((size_t)(n0 + row) * R + r) * D + sg]) = qv;
        }
    }

    f32x4 sacc[2] = {{0.f, 0.f, 0.f, 0.f}, {0.f, 0.f, 0.f, 0.f}};
    #pragma unroll
    for (int kk = 0; kk < 2; kk++) {
        int hrow = 16 * w + lrow;
        const float* hp = hs + hrow * 68 + kk * 32 + lg * 8;
        float4 f0 = *reinterpret_cast<const float4*>(hp);
        float4 f1 = *reinterpret_cast<const float4*>(hp + 4);
        bf16x8 ha;
        ha[0] = (__bf16)f0.x; ha[1] = (__bf16)f0.y; ha[2] = (__bf16)f0.z; ha[3] = (__bf16)f0.w;
        ha[4] = (__bf16)f1.x; ha[5] = (__bf16)f1.y; ha[6] = (__bf16)f1.z; ha[7] = (__bf16)f1.w;
        int koff = (kk * 32 + lg * 8) * 2;
        #pragma unroll
        for (int c = 0; c < 2; c++) {
            int boff = (16 * c + lrow) * 128 + (koff ^ swz);
            bf16x8 bw = *reinterpret_cast<const bf16x8*>(L + OFF_ATTW + boff);
            sacc[c] = __builtin_amdgcn_mfma_f32_16x16x32_bf16(ha, bw, sacc[c], 0, 0, 0);
        }
    }
    float tot = 0.f;
    #pragma unroll
    for (int c = 0; c < 2; c++) {
        int m = 16 * c + lrow;
        float ab = attb[m], av = attv[m];
        #pragma unroll
        for (int reg = 0; reg < 4; reg++) {
            int node = n0 + 16 * w + lg * 4 + reg;
            float tv = tanhf(sacc[c][reg] + ab) * av;
            tot += (node < N) ? tv : 0.f;
        }
    }
    for (int o = 1; o < 64; o <<= 1) tot += __shfl_xor(tot, o);
    if (l == 0) atomicAdd(&wspread[r * 1024 + (blockIdx.x & 1023)], tot);
}

// beta + self-zero of wspread for the next layer (drops one memset launch)
__global__ void k_beta(float* __restrict__ wspread, float* __restrict__ beta, int N) {
    __shared__ float sums[4];
    int wid = threadIdx.x >> 6, lane = threadIdx.x & 63;
    float s = 0.f;
    for (int i = lane; i < 1024; i += 64) s += wspread[wid * 1024 + i];
    for (int o = 32; o > 0; o >>= 1) s += __shfl_down(s, o);
    if (lane == 0) sums[wid] = s;
    __syncthreads();
    if (threadIdx.x == 0) {
        float mean[R], m = -1e30f;
        for (int r = 0; r < R; r++) { mean[r] = sums[r] / (float)N; m = fmaxf(m, mean[r]); }
        float e[R], tot = 0.f;
        for (int r = 0; r < R; r++) { e[r] = expf(mean[r] - m); tot += e[r]; }
        for (int r = 0; r < R; r++) beta[r] = e[r] / tot;
    }
    // all reads of wspread are complete (pre-barrier); zero for next layer
    for (int i = threadIdx.x; i < R * 1024; i += 256) wspread[i] = 0.f;
}

// combine over int16 h: fp32 out only when dow; int16 re-quant when doq
__global__ void k_combine(const short* __restrict__ hq, const float* __restrict__ beta,
                          float* __restrict__ out, short* __restrict__ xq,
                          int doq, int dow, int N) {
    int idx = blockIdx.x * blockDim.x + threadIdx.x;
    int n = idx >> 3, q = idx & 7;
    if (n >= N) return;
    float b0 = beta[0] * (1.f / QSCALE), b1 = beta[1] * (1.f / QSCALE);
    float b2 = beta[2] * (1.f / QSCALE), b3 = beta[3] * (1.f / QSCALE);
    const short8_t* hp = reinterpret_cast<const short8_t*>(&hq[(size_t)n * R * D]);
    short8_t v0 = hp[q], v1 = hp[8 + q], v2 = hp[16 + q], v3 = hp[24 + q];
    float o[8];
    #pragma unroll
    for (int j = 0; j < 8; j++)
        o[j] = b0 * (float)v0[j] + b1 * (float)v1[j] + b2 * (float)v2[j] + b3 * (float)v3[j];
    if (dow) {
        float4 oa = {o[0], o[1], o[2], o[3]};
        float4 ob = {o[4], o[5], o[6], o[7]};
        float4* op = reinterpret_cast<float4*>(&out[(size_t)n * D + q * 8]);
        op[0] = oa;
        op[1] = ob;
    }
    if (doq) {
        short8_t qv;
        #pragma unroll
        for (int j = 0; j < 8; j++) {
            float f = fminf(fmaxf(o[j] * QSCALE, -32767.f), 32767.f);
            qv[j] = (short)(int)rintf(f);
        }
        reinterpret_cast<short8_t*>(&xq[(size_t)n * D + q * 8])[0] = qv;
    }
}

extern "C" void kernel_launch(void* const* d_in, const int* in_sizes, int n_in,
                              void* d_out, int out_size, void* d_ws, size_t ws_size,
                              hipStream_t stream) {
    const float* x   = (const float*)d_in[0];
    const int*   src = (const int*)d_in[1];
    const int*   dst = (const int*)d_in[2];
    const float* W1  = (const float*)d_in[3];
    const float* b1  = (const float*)d_in[4];
    const float* a1W = (const float*)d_in[5];
    const float* a1b = (const float*)d_in[6];
    const float* a1v = (const float*)d_in[7];
    const float* W2  = (const float*)d_in[8];
    const float* b2  = (const float*)d_in[9];
    const float* a2W = (const float*)d_in[10];
    const float* a2b = (const float*)d_in[11];
    const float* a2v = (const float*)d_in[12];

    int N = in_sizes[0] / D;
    int E = in_sizes[1] / R;
    int RN = R * N;
    int nrange = (N + SRANGE - 1) >> SSH;   // 49 for N=100000
    int nbuck = R * nrange;                 // 196
    float* out = (float*)d_out;

    char* ws = (char*)d_ws;
    short* aggq    = (short*)ws; ws += (size_t)N * R * D * 2;   // agg/h int16, in-place
    int*   degi    = (int*)ws;   ws += (size_t)RN * 4;
    int*   offs    = (int*)ws;   ws += (size_t)RN * 4;
    int*   esrc    = (int*)ws;   ws += (size_t)R * E * 4;
    int*   staged  = (int*)ws;   ws += (size_t)R * E * 4;
    short* xq      = (short*)ws; ws += (size_t)N * D * 2;
    int*   bcount  = (int*)ws;   ws += 1024;
    int*   bstart  = (int*)ws;   ws += 1040;
    int*   gcur    = (int*)ws;   ws += 1024;
    float* wspread = (float*)ws; ws += (size_t)R * 1024 * 4;
    float* beta    = (float*)ws; ws += 64;
    __bf16* WtHi   = (__bf16*)ws; ws += 2 * R * 4096 * 2;
    __bf16* WtLo   = (__bf16*)ws; ws += 2 * R * 4096 * 2;
    __bf16* attWHi = (__bf16*)ws; ws += 2 * 2048 * 2;

    // ---- weight precompute + input quantization ----
    k_prep<<<144, 256, 0, stream>>>(W1, W2, a1W, a2W, WtHi, WtLo, attWHi);
    int total4 = N * D / 4;
    k_quant<<<(total4 + 255) / 256, 256, 0, stream>>>(x, xq, total4);

    // ---- CSR build: radix partition + fused per-bucket hist/scan/fill ----
    hipMemsetAsync(bcount, 0, (size_t)nbuck * 4, stream);
    k_bcount<<<dim3(128, R), 256, 0, stream>>>(dst, bcount, E, nrange);
    k_bscan<<<1, 256, 0, stream>>>(bcount, bstart, gcur, nbuck);
    k_part<<<dim3(128, R), 512, 0, stream>>>(src, dst, gcur, staged, E, nrange);
    k_csr2<<<nbuck, 1024, 0, stream>>>(staged, bstart, offs, degi, esrc, N, nrange);

    // wspread zero once; k_beta self-zeroes for layer 1
    hipMemsetAsync(wspread, 0, (size_t)R * 1024 * 4, stream);

    int nbg = (N + 63) / 64;
    for (int layer = 0; layer < 2; layer++) {
        const float* bb = layer ? b2 : b1;
        const float* ab = layer ? a2b : a1b;
        const float* av = layer ? a2v : a1v;
        const __bf16* wh = WtHi + (size_t)layer * 16384;
        const __bf16* wl = WtLo + (size_t)layer * 16384;
        const __bf16* aw = attWHi + (size_t)layer * 2048;

        k_gather<<<N, 256, 0, stream>>>(xq, esrc, offs, degi, aggq, N);
        k_rgemm<<<dim3(nbg, R), 256, 0, stream>>>(aggq, wh, wl, aw, bb, ab, av, wspread, N);
        k_beta<<<1, 256, 0, stream>>>(wspread, beta, N);
        // layer 0: quantize only (out write is dead); layer 1: fp32 out only
        k_combine<<<(N * 8 + 255) / 256, 256, 0, stream>>>(
            aggq, beta, out, xq, layer == 0 ? 1 : 0, layer == 0 ? 0 : 1, N);
    }
}

// Round 14
// 680.780 us; speedup vs baseline: 2.2311x; 1.0551x over previous
//
#include <hip/hip_runtime.h>

#define D 64
#define R 4
#define H_ATT 32
#define SSH 11              // dst-range size shift: S = 2048 nodes
#define SRANGE 2048
#define MAXRANGE 64         // max ranges/relation (N <= 131072)
#define PACK_SH 19          // staged word = (d_local << 19) | src  (N < 524288)
#define QSCALE 4096.0f
#define BCAP 49152          // bucket capacity (expected ~32.6K +- 0.2K; huge margin)

typedef __bf16 bf16x4 __attribute__((ext_vector_type(4)));
typedef __bf16 bf16x8 __attribute__((ext_vector_type(8)));
typedef float f32x4 __attribute__((ext_vector_type(4)));
typedef short short4_t __attribute__((ext_vector_type(4)));
typedef short short8_t __attribute__((ext_vector_type(8)));

// ============ CSR build: capacity buckets -> single-pass radix partition ============

__global__ void k_initcur(int* __restrict__ gcur, int nbuck) {
    int i = threadIdx.x + blockIdx.x * 256;
    if (i < nbuck) gcur[i] = i * BCAP;
}

__global__ __launch_bounds__(512) void k_part(const int* __restrict__ src,
                                              const int* __restrict__ dst,
                                              int* __restrict__ gcur,
                                              int* __restrict__ staged,
                                              int E, int nrange) {
    __shared__ int cnt[MAXRANGE];
    __shared__ int gbase[MAXRANGE];
    int r = blockIdx.y;
    const int* dstr = dst + (size_t)r * E;
    const int* srcr = src + (size_t)r * E;
    int* gcr = gcur + r * nrange;
    int t = threadIdx.x;
    int nsb = (E + 4095) >> 12;
    for (int sb = blockIdx.x; sb < nsb; sb += gridDim.x) {
        int e0 = sb << 12;
        for (int i = t; i < nrange; i += 512) cnt[i] = 0;
        __syncthreads();
        int pk[8], rk[8], lb[8];
        bool val[8];
        for (int u = 0; u < 8; u++) {
            int e = e0 + u * 512 + t;
            val[u] = e < E;
            if (val[u]) {
                int d = __builtin_nontemporal_load(&dstr[e]);
                int s = __builtin_nontemporal_load(&srcr[e]);
                lb[u] = d >> SSH;
                pk[u] = ((d & (SRANGE - 1)) << PACK_SH) | s;
                rk[u] = atomicAdd(&cnt[lb[u]], 1);
            }
        }
        __syncthreads();
        for (int i = t; i < nrange; i += 512) {
            int c = cnt[i];
            gbase[i] = c ? atomicAdd(&gcr[i], c) : 0;
        }
        __syncthreads();
        for (int u = 0; u < 8; u++) {
            if (val[u])
                __builtin_nontemporal_store(pk[u], &staged[gbase[lb[u]] + rk[u]]);
        }
        __syncthreads();
    }
}

// Fused per-bucket: LDS degree hist -> block scan -> offs/degi -> cursor fill.
// Bucket region is [b*BCAP, gcur[b]).
__global__ __launch_bounds__(1024) void k_csr2(const int* __restrict__ staged,
                                               const int* __restrict__ gcur,
                                               int* __restrict__ offs,
                                               int* __restrict__ degi,
                                               int* __restrict__ esrc,
                                               int N, int nrange) {
    __shared__ int hist[SRANGE];
    __shared__ int wp[16];
    int b = blockIdx.x;
    int r = b / nrange, range = b - r * nrange;
    int base = range << SSH;
    int slen = min(SRANGE, N - base);
    int t = threadIdx.x;
    for (int i = t; i < SRANGE; i += 1024) hist[i] = 0;
    __syncthreads();
    int p0 = b * BCAP, p1 = gcur[b];
    for (int p = p0 + t; p < p1; p += 1024)
        atomicAdd(&hist[(unsigned)staged[p] >> PACK_SH], 1);
    __syncthreads();
    int a0 = hist[2 * t], a1 = hist[2 * t + 1];
    int s = a0 + a1;
    int lane = t & 63, wid = t >> 6;
    int x = s;
    for (int o = 1; o < 64; o <<= 1) {
        int y = __shfl_up(x, o);
        if (lane >= o) x += y;
    }
    if (lane == 63) wp[wid] = x;
    __syncthreads();
    if (t == 0) {
        int run = 0;
        for (int i = 0; i < 16; i++) { int v = wp[i]; wp[i] = run; run += v; }
    }
    __syncthreads();
    int ex = wp[wid] + (x - s);
    hist[2 * t] = ex;
    hist[2 * t + 1] = ex + a0;
    if (2 * t < slen) {
        offs[r * N + base + 2 * t] = p0 + ex;
        degi[r * N + base + 2 * t] = a0;
    }
    if (2 * t + 1 < slen) {
        offs[r * N + base + 2 * t + 1] = p0 + ex + a0;
        degi[r * N + base + 2 * t + 1] = a1;
    }
    __syncthreads();
    for (int p = p0 + t; p < p1; p += 1024) {
        int w = staged[p];
        int dloc = (unsigned)w >> PACK_SH;
        int pos = p0 + atomicAdd(&hist[dloc], 1);
        esrc[pos] = w & ((1 << PACK_SH) - 1);
    }
}

// ============ weight precompute: transposed bf16 hi/lo (once per call) ============
__global__ void k_prep(const float* __restrict__ W1, const float* __restrict__ W2,
                       const float* __restrict__ a1W, const float* __restrict__ a2W,
                       __bf16* __restrict__ WtHi, __bf16* __restrict__ WtLo,
                       __bf16* __restrict__ attWtHi) {
    int idx = blockIdx.x * 256 + threadIdx.x;
    if (idx < 32768) {
        int layer = idx >> 14;
        int rem = idx & 16383;
        int r = rem >> 12;
        int ce = rem & 4095;
        int c = ce >> 6, k = ce & 63;
        const float* W = layer ? W2 : W1;
        float w = W[r * 4096 + k * 64 + c];
        __bf16 hi = (__bf16)w;
        __bf16 lo = (__bf16)(w - (float)hi);
        WtHi[idx] = hi;
        WtLo[idx] = lo;
    } else if (idx < 32768 + 4096) {
        int i2 = idx - 32768;
        int layer = i2 >> 11;
        int rem = i2 & 2047;
        int m = rem >> 6, k = rem & 63;
        const float* aW = layer ? a2W : a1W;
        attWtHi[i2] = (__bf16)(aW[k * H_ATT + m]);
    }
}

// ============ int16 quantization of gather operand ============
__global__ void k_quant(const float* __restrict__ xin, short* __restrict__ xq, int total4) {
    int idx = blockIdx.x * 256 + threadIdx.x;
    if (idx >= total4) return;
    float4 v = reinterpret_cast<const float4*>(xin)[idx];
    short4_t q;
    int a;
    a = (int)rintf(v.x * QSCALE); a = min(max(a, -32767), 32767); q[0] = (short)a;
    a = (int)rintf(v.y * QSCALE); a = min(max(a, -32767), 32767); q[1] = (short)a;
    a = (int)rintf(v.z * QSCALE); a = min(max(a, -32767), 32767); q[2] = (short)a;
    a = (int)rintf(v.w * QSCALE); a = min(max(a, -32767), 32767); q[3] = (short)a;
    reinterpret_cast<short4_t*>(xq)[idx] = q;
}

// ============ per-layer kernels ============

// gather (champion structure): one block per node, wave w = relation w; int16 rows,
// 2 edges per 4B-lane load, exact int32 accum, int16 agg output.
__global__ __launch_bounds__(256) void k_gather(const short* __restrict__ xq,
                                                const int* __restrict__ esrc,
                                                const int* __restrict__ offs,
                                                const int* __restrict__ degi,
                                                short* __restrict__ aggq, int N) {
    int n = blockIdx.x;
    int w = threadIdx.x >> 6;
    int l = threadIdx.x & 63;
    unsigned fb = (unsigned)(l & 31) * 4u;
    int g = l >> 5;
    int idx = w * N + n;
    int eo = offs[idx];
    int cnt = degi[idx];
    const char* xb = (const char*)xq;
    int a0 = 0, a1 = 0;
    for (int b0 = 0; b0 < cnt; b0 += 64) {
        int lim = cnt - b0;
        lim = lim < 64 ? lim : 64;
        int sv = (l < lim) ? esrc[eo + b0 + l] : 0;
        int j = 0;
        for (; j + 16 <= lim; j += 16) {
            int ss[8];
            #pragma unroll
            for (int u = 0; u < 8; u++) ss[u] = __shfl(sv, j + 2 * u + g);
            int vv[8];
            #pragma unroll
            for (int u = 0; u < 8; u++)
                vv[u] = *(const int*)(xb + ((unsigned)ss[u] * 128u + fb));
            #pragma unroll
            for (int u = 0; u < 8; u++) {
                a0 += (int)(short)(vv[u] & 0xffff);
                a1 += (vv[u] >> 16);
            }
        }
        for (; j + 2 <= lim; j += 2) {
            int s = __shfl(sv, j + g);
            int v = *(const int*)(xb + ((unsigned)s * 128u + fb));
            a0 += (int)(short)(v & 0xffff);
            a1 += (v >> 16);
        }
        if (j < lim) {
            int s = __shfl(sv, j);
            if (g == 0) {
                int v = *(const int*)(xb + ((unsigned)s * 128u + fb));
                a0 += (int)(short)(v & 0xffff);
                a1 += (v >> 16);
            }
        }
    }
    a0 += __shfl_xor(a0, 32);
    a1 += __shfl_xor(a1, 32);
    float inv = 1.f / fmaxf((float)cnt, 1.f);
    int q = (int)rintf((float)(g ? a1 : a0) * inv);
    aggq[((size_t)n * R + w) * D + (l & 31) * 2 + g] = (short)q;
}

// Fused: h = relu(agg @ W[r] + b[r]) via split-bf16 MFMA; score via bf16 MFMA.
// agg/h are int16 in QSCALE units; in-place (block reads its rows before writing).
#define OFF_A_HI 0
#define OFF_A_LO 8192
#define OFF_B_HI 16384
#define OFF_B_LO 24576
#define OFF_ATTW 32768
__global__ __launch_bounds__(256) void k_rgemm(
        short* hbuf, const __bf16* __restrict__ WtHi, const __bf16* __restrict__ WtLo,
        const __bf16* __restrict__ attWHi, const float* __restrict__ bias,
        const float* __restrict__ attb, const float* __restrict__ attv,
        float* __restrict__ wspread, int N) {
    __shared__ __align__(16) char L[36864];
    float* hs = (float*)L;
    int t = threadIdx.x;
    int r = blockIdx.y;
    int n0 = blockIdx.x * 64;
    const float IQ = 1.f / QSCALE;

    for (int rep = 0; rep < 4; rep++) {
        int row = rep * 16 + (t >> 4);
        int kq = (t & 15) * 4;
        short4_t qv = {0, 0, 0, 0};
        if (n0 + row < N)
            qv = *reinterpret_cast<const short4_t*>(&hbuf[((size_t)(n0 + row) * R + r) * D + kq]);
        bf16x4 hv, lv;
        for (int j = 0; j < 4; j++) {
            float f = (float)qv[j] * IQ;
            __bf16 h = (__bf16)f;
            hv[j] = h;
            lv[j] = (__bf16)(f - (float)h);
        }
        int boff = row * 128 + ((kq * 2) ^ ((row & 7) << 4));
        *reinterpret_cast<bf16x4*>(L + OFF_A_HI + boff) = hv;
        *reinterpret_cast<bf16x4*>(L + OFF_A_LO + boff) = lv;
    }
    {
        const char* gh = (const char*)(WtHi + (size_t)r * 4096);
        const char* gl = (const char*)(WtLo + (size_t)r * 4096);
        for (int rep = 0; rep < 2; rep++) {
            int idx = rep * 256 + t;
            int c = idx >> 3;
            int ko = (idx & 7) * 16;
            int boff = c * 128 + (ko ^ ((c & 7) << 4));
            *reinterpret_cast<uint4*>(L + OFF_B_HI + boff) =
                *reinterpret_cast<const uint4*>(gh + idx * 16);
            *reinterpret_cast<uint4*>(L + OFF_B_LO + boff) =
                *reinterpret_cast<const uint4*>(gl + idx * 16);
        }
        const char* ga = (const char*)attWHi;
        int c = t >> 3;
        int ko = (t & 7) * 16;
        int boff = c * 128 + (ko ^ ((c & 7) << 4));
        *reinterpret_cast<uint4*>(L + OFF_ATTW + boff) =
            *reinterpret_cast<const uint4*>(ga + t * 16);
    }
    __syncthreads();

    int w = t >> 6, l = t & 63;
    int lrow = l & 15, lg = l >> 4;
    int swz = (lrow & 7) << 4;

    f32x4 acc[4] = {{0.f, 0.f, 0.f, 0.f}, {0.f, 0.f, 0.f, 0.f},
                    {0.f, 0.f, 0.f, 0.f}, {0.f, 0.f, 0.f, 0.f}};
    #pragma unroll
    for (int kk = 0; kk < 2; kk++) {
        int koff = (kk * 32 + lg * 8) * 2;
        int aoff = (16 * w + lrow) * 128 + (koff ^ swz);
        bf16x8 ahi = *reinterpret_cast<const bf16x8*>(L + OFF_A_HI + aoff);
        bf16x8 alo = *reinterpret_cast<const bf16x8*>(L + OFF_A_LO + aoff);
        #pragma unroll
        for (int c = 0; c < 4; c++) {
            int boff = (16 * c + lrow) * 128 + (koff ^ swz);
            bf16x8 bhi = *reinterpret_cast<const bf16x8*>(L + OFF_B_HI + boff);
            bf16x8 blo = *reinterpret_cast<const bf16x8*>(L + OFF_B_LO + boff);
            acc[c] = __builtin_amdgcn_mfma_f32_16x16x32_bf16(ahi, bhi, acc[c], 0, 0, 0);
            acc[c] = __builtin_amdgcn_mfma_f32_16x16x32_bf16(ahi, blo, acc[c], 0, 0, 0);
            acc[c] = __builtin_amdgcn_mfma_f32_16x16x32_bf16(alo, bhi, acc[c], 0, 0, 0);
        }
    }
    __syncthreads();

    #pragma unroll
    for (int c = 0; c < 4; c++) {
        int col = 16 * c + lrow;
        float bv = bias[r * D + col];
        #pragma unroll
        for (int reg = 0; reg < 4; reg++) {
            int row = 16 * w + lg * 4 + reg;
            hs[row * 68 + col] = fmaxf(acc[c][reg] + bv, 0.f);
        }
    }
    __syncthreads();

    for (int jj = 0; jj < 4; jj++) {
        int idx = jj * 256 + t;
        int row = idx >> 4;
        int sg = (idx & 15) * 4;
        if (n0 + row < N) {
            float4 v = *reinterpret_cast<const float4*>(&hs[row * 68 + sg]);
            short4_t qv;
            float f;
            f = fminf(fmaxf(v.x * QSCALE, -32767.f), 32767.f); qv[0] = (short)(int)rintf(f);
            f = fminf(fmaxf(v.y * QSCALE, -32767.f), 32767.f); qv[1] = (short)(int)rintf(f);
            f = fminf(fmaxf(v.z * QSCALE, -32767.f), 32767.f); qv[2] = (short)(int)rintf(f);
            f = fminf(fmaxf(v.w * QSCALE, -32767.f), 32767.f); qv[3] = (short)(int)rintf(f);
            *reinterpret_cast<short4_t*>(&hbuf[((size_t)(n0 + row) * R + r) * D + sg]) = qv;
        }
    }

    f32x4 sacc[2] = {{0.f, 0.f, 0.f, 0.f}, {0.f, 0.f, 0.f, 0.f}};
    #pragma unroll
    for (int kk = 0; kk < 2; kk++) {
        int hrow = 16 * w + lrow;
        const float* hp = hs + hrow * 68 + kk * 32 + lg * 8;
        float4 f0 = *reinterpret_cast<const float4*>(hp);
        float4 f1 = *reinterpret_cast<const float4*>(hp + 4);
        bf16x8 ha;
        ha[0] = (__bf16)f0.x; ha[1] = (__bf16)f0.y; ha[2] = (__bf16)f0.z; ha[3] = (__bf16)f0.w;
        ha[4] = (__bf16)f1.x; ha[5] = (__bf16)f1.y; ha[6] = (__bf16)f1.z; ha[7] = (__bf16)f1.w;
        int koff = (kk * 32 + lg * 8) * 2;
        #pragma unroll
        for (int c = 0; c < 2; c++) {
            int boff = (16 * c + lrow) * 128 + (koff ^ swz);
            bf16x8 bw = *reinterpret_cast<const bf16x8*>(L + OFF_ATTW + boff);
            sacc[c] = __builtin_amdgcn_mfma_f32_16x16x32_bf16(ha, bw, sacc[c], 0, 0, 0);
        }
    }
    float tot = 0.f;
    #pragma unroll
    for (int c = 0; c < 2; c++) {
        int m = 16 * c + lrow;
        float ab = attb[m], av = attv[m];
        #pragma unroll
        for (int reg = 0; reg < 4; reg++) {
            int node = n0 + 16 * w + lg * 4 + reg;
            float tv = tanhf(sacc[c][reg] + ab) * av;
            tot += (node < N) ? tv : 0.f;
        }
    }
    for (int o = 1; o < 64; o <<= 1) tot += __shfl_xor(tot, o);
    if (l == 0) atomicAdd(&wspread[r * 1024 + (blockIdx.x & 1023)], tot);
}

// beta + self-zero of wspread for the next layer (drops one memset launch)
__global__ void k_beta(float* __restrict__ wspread, float* __restrict__ beta, int N) {
    __shared__ float sums[4];
    int wid = threadIdx.x >> 6, lane = threadIdx.x & 63;
    float s = 0.f;
    for (int i = lane; i < 1024; i += 64) s += wspread[wid * 1024 + i];
    for (int o = 32; o > 0; o >>= 1) s += __shfl_down(s, o);
    if (lane == 0) sums[wid] = s;
    __syncthreads();
    if (threadIdx.x == 0) {
        float mean[R], m = -1e30f;
        for (int r = 0; r < R; r++) { mean[r] = sums[r] / (float)N; m = fmaxf(m, mean[r]); }
        float e[R], tot = 0.f;
        for (int r = 0; r < R; r++) { e[r] = expf(mean[r] - m); tot += e[r]; }
        for (int r = 0; r < R; r++) beta[r] = e[r] / tot;
    }
    // all reads of wspread are complete (pre-barrier); zero for next layer
    for (int i = threadIdx.x; i < R * 1024; i += 256) wspread[i] = 0.f;
}

// combine over int16 h: fp32 out only when dow; int16 re-quant when doq
__global__ void k_combine(const short* __restrict__ hq, const float* __restrict__ beta,
                          float* __restrict__ out, short* __restrict__ xq,
                          int doq, int dow, int N) {
    int idx = blockIdx.x * blockDim.x + threadIdx.x;
    int n = idx >> 3, q = idx & 7;
    if (n >= N) return;
    float b0 = beta[0] * (1.f / QSCALE), b1 = beta[1] * (1.f / QSCALE);
    float b2 = beta[2] * (1.f / QSCALE), b3 = beta[3] * (1.f / QSCALE);
    const short8_t* hp = reinterpret_cast<const short8_t*>(&hq[(size_t)n * R * D]);
    short8_t v0 = hp[q], v1 = hp[8 + q], v2 = hp[16 + q], v3 = hp[24 + q];
    float o[8];
    #pragma unroll
    for (int j = 0; j < 8; j++)
        o[j] = b0 * (float)v0[j] + b1 * (float)v1[j] + b2 * (float)v2[j] + b3 * (float)v3[j];
    if (dow) {
        float4 oa = {o[0], o[1], o[2], o[3]};
        float4 ob = {o[4], o[5], o[6], o[7]};
        float4* op = reinterpret_cast<float4*>(&out[(size_t)n * D + q * 8]);
        op[0] = oa;
        op[1] = ob;
    }
    if (doq) {
        short8_t qv;
        #pragma unroll
        for (int j = 0; j < 8; j++) {
            float f = fminf(fmaxf(o[j] * QSCALE, -32767.f), 32767.f);
            qv[j] = (short)(int)rintf(f);
        }
        reinterpret_cast<short8_t*>(&xq[(size_t)n * D + q * 8])[0] = qv;
    }
}

extern "C" void kernel_launch(void* const* d_in, const int* in_sizes, int n_in,
                              void* d_out, int out_size, void* d_ws, size_t ws_size,
                              hipStream_t stream) {
    const float* x   = (const float*)d_in[0];
    const int*   src = (const int*)d_in[1];
    const int*   dst = (const int*)d_in[2];
    const float* W1  = (const float*)d_in[3];
    const float* b1  = (const float*)d_in[4];
    const float* a1W = (const float*)d_in[5];
    const float* a1b = (const float*)d_in[6];
    const float* a1v = (const float*)d_in[7];
    const float* W2  = (const float*)d_in[8];
    const float* b2  = (const float*)d_in[9];
    const float* a2W = (const float*)d_in[10];
    const float* a2b = (const float*)d_in[11];
    const float* a2v = (const float*)d_in[12];

    int N = in_sizes[0] / D;
    int E = in_sizes[1] / R;
    int RN = R * N;
    int nrange = (N + SRANGE - 1) >> SSH;   // 49 for N=100000
    int nbuck = R * nrange;                 // 196
    float* out = (float*)d_out;

    char* ws = (char*)d_ws;
    short* aggq    = (short*)ws; ws += (size_t)N * R * D * 2;   // agg/h int16, in-place
    int*   degi    = (int*)ws;   ws += (size_t)RN * 4;
    int*   offs    = (int*)ws;   ws += (size_t)RN * 4;
    int*   esrc    = (int*)ws;   ws += (size_t)nbuck * BCAP * 4;
    int*   staged  = (int*)ws;   ws += (size_t)nbuck * BCAP * 4;
    short* xq      = (short*)ws; ws += (size_t)N * D * 2;
    int*   gcur    = (int*)ws;   ws += 1024;
    float* wspread = (float*)ws; ws += (size_t)R * 1024 * 4;
    float* beta    = (float*)ws; ws += 64;
    __bf16* WtHi   = (__bf16*)ws; ws += 2 * R * 4096 * 2;
    __bf16* WtLo   = (__bf16*)ws; ws += 2 * R * 4096 * 2;
    __bf16* attWHi = (__bf16*)ws; ws += 2 * 2048 * 2;

    // ---- weight precompute + input quantization ----
    k_prep<<<144, 256, 0, stream>>>(W1, W2, a1W, a2W, WtHi, WtLo, attWHi);
    int total4 = N * D / 4;
    k_quant<<<(total4 + 255) / 256, 256, 0, stream>>>(x, xq, total4);

    // ---- CSR build: capacity buckets, radix partition + fused hist/scan/fill ----
    k_initcur<<<1, 256, 0, stream>>>(gcur, nbuck);
    k_part<<<dim3(128, R), 512, 0, stream>>>(src, dst, gcur, staged, E, nrange);
    k_csr2<<<nbuck, 1024, 0, stream>>>(staged, gcur, offs, degi, esrc, N, nrange);

    // wspread zero once; k_beta self-zeroes for layer 1
    hipMemsetAsync(wspread, 0, (size_t)R * 1024 * 4, stream);

    int nbg = (N + 63) / 64;
    for (int layer = 0; layer < 2; layer++) {
        const float* bb = layer ? b2 : b1;
        const float* ab = layer ? a2b : a1b;
        const float* av = layer ? a2v : a1v;
        const __bf16* wh = WtHi + (size_t)layer * 16384;
        const __bf16* wl = WtLo + (size_t)layer * 16384;
        const __bf16* aw = attWHi + (size_t)layer * 2048;

        k_gather<<<N, 256, 0, stream>>>(xq, esrc, offs, degi, aggq, N);
        k_rgemm<<<dim3(nbg, R), 256, 0, stream>>>(aggq, wh, wl, aw, bb, ab, av, wspread, N);
        k_beta<<<1, 256, 0, stream>>>(wspread, beta, N);
        // layer 0: quantize only (out write is dead); layer 1: fp32 out only
        k_combine<<<(N * 8 + 255) / 256, 256, 0, stream>>>(
            aggq, beta, out, xq, layer == 0 ? 1 : 0, layer == 0 ? 0 : 1, N);
    }
}